// Round 1
// baseline (10677.837 us; speedup 1.0000x reference)
//
#include <hip/hip_runtime.h>
#include <hip/hip_bf16.h>

// Problem constants
#define S_LEN 512
#define BATCH 64
#define DC    200       // per-table embed dim
#define HID   300       // linear out / lstm hidden
#define H4    1200      // 4*H gates
#define IN_DIM 800
#define WT_PAD 1280     // padded gate dim for WhhT so the 5th column chunk needs no mask

__device__ __forceinline__ float sigmoidf_(float x) { return 1.0f / (1.0f + __expf(-x)); }
__device__ __forceinline__ float tanhf_(float x)    { return 2.0f / (1.0f + __expf(-2.0f * x)) - 1.0f; }

// ---------------------------------------------------------------------------
// Pre-pass: transpose Whh [1200,300] -> WhhT [300][1280] (pad cols zeroed)
// so the recurrence streams weights coalesced along the gate dimension.
// ---------------------------------------------------------------------------
__global__ void k_transpose(const float* __restrict__ Wl, const float* __restrict__ Wr,
                            float* __restrict__ Tl, float* __restrict__ Tr) {
    int i = blockIdx.x * 256 + threadIdx.x;
    const int total = HID * WT_PAD;
    if (i >= total) return;
    int k = i / WT_PAD, n = i % WT_PAD;
    float vl = 0.f, vr = 0.f;
    if (n < H4) { vl = Wl[n * HID + k]; vr = Wr[n * HID + k]; }
    Tl[i] = vl; Tr[i] = vr;
}

// ---------------------------------------------------------------------------
// K1: fused embedding-gather + linear + tanh.
//   out[m, n] = tanh( sum_k concat(ce[cf],sce[scf],be[dyn],sbe[stat])[m,k] * W[n,k] + bias[n] )
//   m = b*512+s (0..32767), z=0 -> left (bl,sbl), z=1 -> right (br,sbr)
// Classic 64x64x16 f32 tile, 256 thr, 4x4 microtile.
// ---------------------------------------------------------------------------
__global__ __launch_bounds__(256) void k_lin(
    const int* __restrict__ cf, const int* __restrict__ bl, const int* __restrict__ br,
    const int* __restrict__ scf, const int* __restrict__ sbl, const int* __restrict__ sbr,
    const float* __restrict__ ce, const float* __restrict__ be,
    const float* __restrict__ sce, const float* __restrict__ sbe,
    const float* __restrict__ W, const float* __restrict__ bias,
    float* __restrict__ outL, float* __restrict__ outR)
{
    const int z = blockIdx.z;
    const int* dynIdx  = z ? br  : bl;
    const int* statIdx = z ? sbr : sbl;
    float* outp = z ? outR : outL;
    const int m0 = blockIdx.x * 64;
    const int n0 = blockIdx.y * 64;
    __shared__ float As[16][68];
    __shared__ float Bs[16][68];
    const int t  = threadIdx.x;
    const int lk = t & 15;        // k within tile (coalesced dim on loads)
    const int lm = t >> 4;        // row/col within tile
    const int tx = t & 15, ty = t >> 4;
    float acc[4][4] = {};

    for (int k0 = 0; k0 < IN_DIM; k0 += 16) {
        const int kk  = k0 + lk;
        const int seg = kk / 200;          // 0:char 1:static_char 2:bichar 3:static_bichar
        const int kin = kk - seg * 200;
        const int*   idxA = (seg == 0) ? cf : (seg == 1) ? scf : (seg == 2) ? dynIdx : statIdx;
        const float* tab  = (seg == 0) ? ce : (seg == 1) ? sce : (seg == 2) ? be     : sbe;
#pragma unroll
        for (int r = 0; r < 4; ++r) {
            int m = m0 + lm + r * 16;
            int id = idxA[m];
            As[lk][lm + r * 16] = tab[(size_t)id * DC + kin];
        }
#pragma unroll
        for (int r = 0; r < 4; ++r) {
            int n = n0 + lm + r * 16;
            Bs[lk][lm + r * 16] = (n < HID) ? W[n * IN_DIM + kk] : 0.f;
        }
        __syncthreads();
#pragma unroll
        for (int kq = 0; kq < 16; ++kq) {
            float a[4], b[4];
#pragma unroll
            for (int i = 0; i < 4; ++i) a[i] = As[kq][ty * 4 + i];
#pragma unroll
            for (int j = 0; j < 4; ++j) b[j] = Bs[kq][tx * 4 + j];
#pragma unroll
            for (int i = 0; i < 4; ++i)
#pragma unroll
                for (int j = 0; j < 4; ++j) acc[i][j] = fmaf(a[i], b[j], acc[i][j]);
        }
        __syncthreads();
    }
#pragma unroll
    for (int i = 0; i < 4; ++i) {
        int m = m0 + ty * 4 + i;
#pragma unroll
        for (int j = 0; j < 4; ++j) {
            int n = n0 + tx * 4 + j;
            if (n < HID) outp[(size_t)m * HID + n] = tanhf_(acc[i][j] + bias[n]);
        }
    }
}

// ---------------------------------------------------------------------------
// K2: x = A @ Wih.T + b   (A=[32768,300] row m=b*512+s; out X[s*64+b, 1200] bf16)
// ---------------------------------------------------------------------------
__global__ __launch_bounds__(256) void k_xgemm(
    const float* __restrict__ A,
    const float* __restrict__ Wih,
    const float* __restrict__ bias,
    __hip_bfloat16* __restrict__ X)
{
    const int m0 = blockIdx.x * 64;
    const int n0 = blockIdx.y * 64;
    __shared__ float As[16][68];
    __shared__ float Bs[16][68];
    const int t = threadIdx.x;
    const int lk = t & 15, lm = t >> 4;
    const int tx = t & 15, ty = t >> 4;
    float acc[4][4] = {};

    for (int k0 = 0; k0 < 304; k0 += 16) {
        const int kk = k0 + lk;
        const bool kok = (kk < HID);
#pragma unroll
        for (int r = 0; r < 4; ++r) {
            int m = m0 + lm + r * 16;
            As[lk][lm + r * 16] = kok ? A[(size_t)m * HID + kk] : 0.f;
        }
#pragma unroll
        for (int r = 0; r < 4; ++r) {
            int n = n0 + lm + r * 16;
            Bs[lk][lm + r * 16] = (kok && n < H4) ? Wih[n * HID + kk] : 0.f;
        }
        __syncthreads();
#pragma unroll
        for (int kq = 0; kq < 16; ++kq) {
            float a[4], b[4];
#pragma unroll
            for (int i = 0; i < 4; ++i) a[i] = As[kq][ty * 4 + i];
#pragma unroll
            for (int j = 0; j < 4; ++j) b[j] = Bs[kq][tx * 4 + j];
#pragma unroll
            for (int i = 0; i < 4; ++i)
#pragma unroll
                for (int j = 0; j < 4; ++j) acc[i][j] = fmaf(a[i], b[j], acc[i][j]);
        }
        __syncthreads();
    }
#pragma unroll
    for (int i = 0; i < 4; ++i) {
        int m = m0 + ty * 4 + i;
        int b = m >> 9, s = m & 511;
        size_t orow = (size_t)(s * BATCH + b);
#pragma unroll
        for (int j = 0; j < 4; ++j) {
            int n = n0 + tx * 4 + j;
            if (n < H4) X[orow * H4 + n] = __float2bfloat16(acc[i][j] + bias[n]);
        }
    }
}

// ---------------------------------------------------------------------------
// K3: LSTM recurrence, batch-split (zero inter-block sync, deterministic).
// 64 blocks: blocks 0..31 = left dir (2 batches each), 32..63 = right dir.
// Per step: gates = x_t + h @ WhhT (streamed), nonlinearity, c/h update, write out.
// Expected bottleneck this round: per-CU weight restream (~1.5MB/step @~150GB/s).
// ---------------------------------------------------------------------------
__global__ __launch_bounds__(256) void k_rec(
    const __hip_bfloat16* __restrict__ XL,
    const __hip_bfloat16* __restrict__ XR,
    const float* __restrict__ WTl,
    const float* __restrict__ WTr,
    float* __restrict__ out)
{
    const int dir = blockIdx.x >> 5;
    const int bp  = blockIdx.x & 31;
    const int b0  = bp * 2;
    const __hip_bfloat16* X = dir ? XR : XL;
    const float* WT = dir ? WTr : WTl;

    __shared__ float hs[2][HID];
    __shared__ float cs[2][HID];
    __shared__ float gl[2][H4];
    const int t = threadIdx.x;
    for (int j = t; j < HID; j += 256) { hs[0][j] = 0.f; hs[1][j] = 0.f; cs[0][j] = 0.f; cs[1][j] = 0.f; }
    __syncthreads();

    const int n4 = 1024 + t;
    const bool has5 = (n4 < H4);

    for (int tau = 0; tau < S_LEN; ++tau) {
        const int s = dir ? (S_LEN - 1 - tau) : tau;
        const __hip_bfloat16* x0 = X + (size_t)(s * BATCH + b0) * H4;
        const __hip_bfloat16* x1 = x0 + H4;
        float g0[5], g1[5];
#pragma unroll
        for (int c = 0; c < 4; ++c) {
            int n = t + c * 256;
            g0[c] = __bfloat162float(x0[n]);
            g1[c] = __bfloat162float(x1[n]);
        }
        g0[4] = has5 ? __bfloat162float(x0[n4]) : 0.f;
        g1[4] = has5 ? __bfloat162float(x1[n4]) : 0.f;

        // gates += h @ WhhT  (h broadcast from LDS, weights streamed coalesced)
        for (int k = 0; k < HID; ++k) {
            float h0 = hs[0][k], h1 = hs[1][k];
            const float* wr = WT + k * WT_PAD;
#pragma unroll
            for (int c = 0; c < 5; ++c) {
                float w = wr[t + c * 256];            // pad cols are zero -> no mask needed
                g0[c] = fmaf(h0, w, g0[c]);
                g1[c] = fmaf(h1, w, g1[c]);
            }
        }
#pragma unroll
        for (int c = 0; c < 5; ++c) {
            int n = t + c * 256;
            if (n < H4) { gl[0][n] = g0[c]; gl[1][n] = g1[c]; }
        }
        __syncthreads();   // gl ready; everyone done reading hs

        for (int j = t; j < HID; j += 256) {
#pragma unroll
            for (int bi = 0; bi < 2; ++bi) {
                float ig = sigmoidf_(gl[bi][j]);
                float fg = sigmoidf_(gl[bi][300 + j]);
                float gg = tanhf_   (gl[bi][600 + j]);
                float og = sigmoidf_(gl[bi][900 + j]);
                float cn = fg * cs[bi][j] + ig * gg;
                cs[bi][j] = cn;
                float hv = og * tanhf_(cn);
                hs[bi][j] = hv;
                out[((size_t)(b0 + bi) * S_LEN + s) * 600 + dir * HID + j] = hv;
            }
        }
        __syncthreads();   // h/c updated before next step's reads
    }
}

// ---------------------------------------------------------------------------
extern "C" void kernel_launch(void* const* d_in, const int* in_sizes, int n_in,
                              void* d_out, int out_size, void* d_ws, size_t ws_size,
                              hipStream_t stream) {
    const int*   cf    = (const int*)d_in[0];
    const int*   bl    = (const int*)d_in[1];
    const int*   br    = (const int*)d_in[2];
    const int*   scf   = (const int*)d_in[3];
    const int*   sbl   = (const int*)d_in[4];
    const int*   sbr   = (const int*)d_in[5];
    const float* ce    = (const float*)d_in[6];
    const float* be    = (const float*)d_in[7];
    const float* sce   = (const float*)d_in[8];
    const float* sbe   = (const float*)d_in[9];
    const float* Wlin  = (const float*)d_in[10];
    const float* blin  = (const float*)d_in[11];
    const float* Wih_l = (const float*)d_in[12];
    const float* Whh_l = (const float*)d_in[13];
    const float* b_l   = (const float*)d_in[14];
    const float* Wih_r = (const float*)d_in[15];
    const float* Whh_r = (const float*)d_in[16];
    const float* b_r   = (const float*)d_in[17];
    float* out = (float*)d_out;

    // Workspace layout (bytes):
    //   left_h  f32 [32768*300]  : 39,321,600
    //   right_h f32 [32768*300]  : 39,321,600
    //   xl bf16 [512*64*1200]    : 78,643,200
    //   xr bf16 [512*64*1200]    : 78,643,200
    //   WhhT_l f32 [300*1280]    :  1,536,000
    //   WhhT_r f32 [300*1280]    :  1,536,000
    //   total: 239,001,600 B (~228 MiB)
    char* ws = (char*)d_ws;
    float* left_h  = (float*)(ws);
    float* right_h = (float*)(ws + 39321600);
    __hip_bfloat16* xl = (__hip_bfloat16*)(ws + 78643200);
    __hip_bfloat16* xr = (__hip_bfloat16*)(ws + 157286400);
    float* WTl = (float*)(ws + 235929600);
    float* WTr = (float*)(ws + 237465600);

    k_transpose<<<dim3((HID * WT_PAD + 255) / 256), dim3(256), 0, stream>>>(Whh_l, Whh_r, WTl, WTr);
    k_lin<<<dim3(512, 5, 2), dim3(256), 0, stream>>>(cf, bl, br, scf, sbl, sbr,
                                                     ce, be, sce, sbe, Wlin, blin,
                                                     left_h, right_h);
    k_xgemm<<<dim3(512, 19), dim3(256), 0, stream>>>(left_h,  Wih_l, b_l, xl);
    k_xgemm<<<dim3(512, 19), dim3(256), 0, stream>>>(right_h, Wih_r, b_r, xr);
    k_rec<<<dim3(64), dim3(256), 0, stream>>>(xl, xr, WTl, WTr, out);
}

// Round 2
// 7531.116 us; speedup vs baseline: 1.4178x; 1.4178x over previous
//
#include <hip/hip_runtime.h>
#include <hip/hip_bf16.h>

// Problem constants
#define S_LEN 512
#define BATCH 64
#define DC    200
#define HID   300
#define H4    1200
#define IN_DIM 800
#define G_SPLIT 10          // gate-blocks per recurrence team (30 h-dims each)

typedef __attribute__((ext_vector_type(8))) short short8b;   // 8 bf16
typedef __attribute__((ext_vector_type(4))) float f32x4;

__device__ __forceinline__ float sigmoidf_(float x) { return 1.0f / (1.0f + __expf(-x)); }
__device__ __forceinline__ float tanhf_(float x)    { return 2.0f / (1.0f + __expf(-2.0f * x)) - 1.0f; }

// ---------------------------------------------------------------------------
// Permuted weight prep. Gate rows reordered so block g owns rows
// [g*128, g*128+128): locals 0..119 = {i,f,g,o} x 30 h-dims (j = g*30+jj),
// locals 120..127 zero pad. K padded 300->320 with zeros. bf16.
// ---------------------------------------------------------------------------
__global__ void k_prep_w(const float* __restrict__ Whh_l, const float* __restrict__ Whh_r,
                         const float* __restrict__ Wih_l, const float* __restrict__ Wih_r,
                         __hip_bfloat16* __restrict__ Whh_p, __hip_bfloat16* __restrict__ Wih_p) {
    int i = blockIdx.x * 256 + threadIdx.x;        // over 2*1280*320
    if (i >= 2 * 1280 * 320) return;
    int k = i % 320;
    int R = (i / 320) % 1280;
    int d = i / (320 * 1280);
    int g = R >> 7, local = R & 127;
    float vh = 0.f, vi = 0.f;
    if (local < 120 && k < 300) {
        int q = local / 30, jj = local % 30;
        int n = q * 300 + g * 30 + jj;
        const float* Whh = d ? Whh_r : Whh_l;
        const float* Wih = d ? Wih_r : Wih_l;
        vh = Whh[n * 300 + k];
        vi = Wih[n * 300 + k];
    }
    Whh_p[i] = __float2bfloat16(vh);
    Wih_p[i] = __float2bfloat16(vi);
}

// Zero h-buffers + counters, build permuted bias. Runs every launch (graph replays).
__global__ void k_prep_misc(const float* __restrict__ b_l, const float* __restrict__ b_r,
                            __hip_bfloat16* __restrict__ hb_hi, __hip_bfloat16* __restrict__ hb_lo,
                            float* __restrict__ bias_p, int* __restrict__ ctr) {
    int i = blockIdx.x * 256 + threadIdx.x;
    if (i < 2 * 2 * 64 * 320) {
        hb_hi[i] = __float2bfloat16(0.f);
        hb_lo[i] = __float2bfloat16(0.f);
    }
    if (i < 2 * 1280) {
        int d = i / 1280, R = i % 1280;
        int g = R >> 7, local = R & 127;
        float v = 0.f;
        if (local < 120) { int q = local / 30, jj = local % 30; v = (d ? b_r : b_l)[q * 300 + g * 30 + jj]; }
        bias_p[i] = v;
    }
    if (i < 8) ctr[i] = 0;
}

// ---------------------------------------------------------------------------
// K1: fused embedding-gather + linear + tanh (f32 compute, bf16 out, stride 320)
// ---------------------------------------------------------------------------
__global__ __launch_bounds__(256) void k_lin(
    const int* __restrict__ cf, const int* __restrict__ bl, const int* __restrict__ br,
    const int* __restrict__ scf, const int* __restrict__ sbl, const int* __restrict__ sbr,
    const float* __restrict__ ce, const float* __restrict__ be,
    const float* __restrict__ sce, const float* __restrict__ sbe,
    const float* __restrict__ W, const float* __restrict__ bias,
    __hip_bfloat16* __restrict__ outL, __hip_bfloat16* __restrict__ outR)
{
    const int z = blockIdx.z;
    const int* dynIdx  = z ? br  : bl;
    const int* statIdx = z ? sbr : sbl;
    __hip_bfloat16* outp = z ? outR : outL;
    const int m0 = blockIdx.x * 64;
    const int n0 = blockIdx.y * 64;
    __shared__ float As[16][68];
    __shared__ float Bs[16][68];
    const int t  = threadIdx.x;
    const int lk = t & 15;
    const int lm = t >> 4;
    const int tx = t & 15, ty = t >> 4;
    float acc[4][4] = {};

    for (int k0 = 0; k0 < IN_DIM; k0 += 16) {
        const int kk  = k0 + lk;
        const int seg = kk / 200;
        const int kin = kk - seg * 200;
        const int*   idxA = (seg == 0) ? cf : (seg == 1) ? scf : (seg == 2) ? dynIdx : statIdx;
        const float* tab  = (seg == 0) ? ce : (seg == 1) ? sce : (seg == 2) ? be     : sbe;
#pragma unroll
        for (int r = 0; r < 4; ++r) {
            int m = m0 + lm + r * 16;
            int id = idxA[m];
            As[lk][lm + r * 16] = tab[(size_t)id * DC + kin];
        }
#pragma unroll
        for (int r = 0; r < 4; ++r) {
            int n = n0 + lm + r * 16;
            Bs[lk][lm + r * 16] = (n < HID) ? W[n * IN_DIM + kk] : 0.f;
        }
        __syncthreads();
#pragma unroll
        for (int kq = 0; kq < 16; ++kq) {
            float a[4], b[4];
#pragma unroll
            for (int i = 0; i < 4; ++i) a[i] = As[kq][ty * 4 + i];
#pragma unroll
            for (int j = 0; j < 4; ++j) b[j] = Bs[kq][tx * 4 + j];
#pragma unroll
            for (int i = 0; i < 4; ++i)
#pragma unroll
                for (int j = 0; j < 4; ++j) acc[i][j] = fmaf(a[i], b[j], acc[i][j]);
        }
        __syncthreads();
    }
#pragma unroll
    for (int i = 0; i < 4; ++i) {
        int m = m0 + ty * 4 + i;
#pragma unroll
        for (int j = 0; j < 4; ++j) {
            int n = n0 + tx * 4 + j;
            float v = (n < HID) ? tanhf_(acc[i][j] + bias[n]) : 0.f;   // zero K-pad 300..319
            outp[(size_t)m * 320 + n] = __float2bfloat16(v);
        }
    }
}

// ---------------------------------------------------------------------------
// K2: X = A @ Wih_p^T + bias_p, bf16 MFMA 16x16x32.
// A [dir][32768][320] bf16 (m=b*512+s), Wih_p [dir][1280][320] bf16 (permuted rows),
// X out [dir][512][64][1280] bf16. Block tile M=64 N=128 K-step 32, 4 waves.
// ---------------------------------------------------------------------------
__global__ __launch_bounds__(256) void k_xgemm(
    const __hip_bfloat16* __restrict__ A,
    const __hip_bfloat16* __restrict__ Wih_p,
    const float* __restrict__ bias_p,
    __hip_bfloat16* __restrict__ Xout)
{
    const int dir = blockIdx.z;
    const int m0 = blockIdx.x * 64;
    const int n0 = blockIdx.y * 128;
    const __hip_bfloat16* Ad = A + (size_t)dir * 32768 * 320;
    const __hip_bfloat16* Wd = Wih_p + (size_t)dir * 1280 * 320;
    const float* bd = bias_p + dir * 1280;
    __hip_bfloat16* Xd = Xout + (size_t)dir * 512 * 64 * 1280;

    __shared__ __hip_bfloat16 sA[64][40];    // +8 bf16 pad: row stride 80B kills bank conflicts
    __shared__ __hip_bfloat16 sB[128][40];
    const int t = threadIdx.x, lane = t & 63, wv = t >> 6;
    f32x4 acc[4][2] = {};

    for (int k0 = 0; k0 < 320; k0 += 32) {
        {
            int r = t >> 2, kg = (t & 3) * 8;
            *reinterpret_cast<short8b*>(&sA[r][kg]) =
                *reinterpret_cast<const short8b*>(Ad + (size_t)(m0 + r) * 320 + k0 + kg);
        }
#pragma unroll
        for (int i = 0; i < 2; ++i) {
            int c = t + i * 256;
            int r = c >> 2, kg = (c & 3) * 8;
            *reinterpret_cast<short8b*>(&sB[r][kg]) =
                *reinterpret_cast<const short8b*>(Wd + (size_t)(n0 + r) * 320 + k0 + kg);
        }
        __syncthreads();
        const int kl = (lane >> 4) * 8;
#pragma unroll
        for (int mt = 0; mt < 4; ++mt) {
            short8b af = *reinterpret_cast<const short8b*>(&sA[mt * 16 + (lane & 15)][kl]);
#pragma unroll
            for (int nt = 0; nt < 2; ++nt) {
                short8b bf = *reinterpret_cast<const short8b*>(&sB[(wv * 2 + nt) * 16 + (lane & 15)][kl]);
                acc[mt][nt] = __builtin_amdgcn_mfma_f32_16x16x32_bf16(af, bf, acc[mt][nt], 0, 0, 0);
            }
        }
        __syncthreads();
    }
#pragma unroll
    for (int mt = 0; mt < 4; ++mt)
#pragma unroll
        for (int nt = 0; nt < 2; ++nt) {
            int p = n0 + (wv * 2 + nt) * 16 + (lane & 15);
            float bv = bd[p];
#pragma unroll
            for (int r = 0; r < 4; ++r) {
                int m = m0 + mt * 16 + (lane >> 4) * 4 + r;
                int b = m >> 9, s = m & 511;
                Xd[(size_t)(s * 64 + b) * 1280 + p] = __float2bfloat16(acc[mt][nt][r] + bv);
            }
        }
}

// ---------------------------------------------------------------------------
// K3: LSTM recurrence — weight-stationary teams.
// 80 blocks = 2 dirs x 4 batch-groups(16) x G_SPLIT gate-blocks(128 perm rows).
// Whh slice LDS-resident bf16. Per step: gates = X + h_hi@W + h_lo@W (MFMA),
// nonlinearity on owned 30 h-dims, publish h (hi/lo bf16, parity dbuf),
// device-scope flag barrier among the 10 teammates.
// ---------------------------------------------------------------------------
__global__ __launch_bounds__(256) void k_rec(
    const __hip_bfloat16* __restrict__ X,      // [2][512][64][1280]
    const __hip_bfloat16* __restrict__ Whh_p,  // [2][1280][320]
    __hip_bfloat16* __restrict__ hb_hi,        // [2][2][64][320]
    __hip_bfloat16* __restrict__ hb_lo,
    int* __restrict__ ctr,                     // [8] per-team monotonic counters
    float* __restrict__ out)                   // [64][512][600]
{
    const int bid = blockIdx.x;
    const int dir = bid / (4 * G_SPLIT);
    const int grp = (bid / G_SPLIT) % 4;
    const int g   = bid % G_SPLIT;
    const int t = threadIdx.x;
    const int lane = t & 63, wv = t >> 6;
    const int b0 = grp * 16;

    __shared__ __hip_bfloat16 sW[128][328];    // row stride 656B -> 2-way (free) on b128 reads
    __shared__ float sG[16][128];
    __shared__ float sC[16][32];

    const __hip_bfloat16* Wsrc = Whh_p + ((size_t)dir * 1280 + g * 128) * 320;
    for (int i = t; i < 128 * 40; i += 256) {
        int r = i / 40, kg = (i % 40) * 8;
        *reinterpret_cast<short8b*>(&sW[r][kg]) = *reinterpret_cast<const short8b*>(Wsrc + r * 320 + kg);
    }
    for (int i = t; i < 16 * 32; i += 256) sC[i >> 5][i & 31] = 0.f;
    __syncthreads();

    int* myctr = ctr + dir * 4 + grp;
    int cnt_target = 0;
    const int n0 = wv * 32;
    const int kl = (lane >> 4) * 8;

    for (int tau = 0; tau < S_LEN; ++tau) {
        const int s = dir ? (S_LEN - 1 - tau) : tau;
        const int par = tau & 1;

        // gates = h_hi @ W + h_lo @ W   (M=16 batches, N=32 per wave, K=320)
        f32x4 acc0 = {0, 0, 0, 0}, acc1 = {0, 0, 0, 0};
        const __hip_bfloat16* hi_b = hb_hi + (((size_t)dir * 2 + par) * 64 + b0 + (lane & 15)) * 320;
        const __hip_bfloat16* lo_b = hb_lo + (((size_t)dir * 2 + par) * 64 + b0 + (lane & 15)) * 320;
        for (int kt = 0; kt < 10; ++kt) {
            short8b ahi = *reinterpret_cast<const short8b*>(hi_b + kt * 32 + kl);
            short8b alo = *reinterpret_cast<const short8b*>(lo_b + kt * 32 + kl);
            short8b bf0 = *reinterpret_cast<const short8b*>(&sW[n0 + (lane & 15)][kt * 32 + kl]);
            short8b bf1 = *reinterpret_cast<const short8b*>(&sW[n0 + 16 + (lane & 15)][kt * 32 + kl]);
            acc0 = __builtin_amdgcn_mfma_f32_16x16x32_bf16(ahi, bf0, acc0, 0, 0, 0);
            acc1 = __builtin_amdgcn_mfma_f32_16x16x32_bf16(ahi, bf1, acc1, 0, 0, 0);
            acc0 = __builtin_amdgcn_mfma_f32_16x16x32_bf16(alo, bf0, acc0, 0, 0, 0);
            acc1 = __builtin_amdgcn_mfma_f32_16x16x32_bf16(alo, bf1, acc1, 0, 0, 0);
        }

        // add x, park gates in LDS
        const __hip_bfloat16* xp = X + (((size_t)dir * 512 + s) * 64 + b0) * 1280 + g * 128;
#pragma unroll
        for (int r = 0; r < 4; ++r) {
            int m = (lane >> 4) * 4 + r;
            int c0 = n0 + (lane & 15), c1 = c0 + 16;
            sG[m][c0] = acc0[r] + __bfloat162float(xp[(size_t)m * 1280 + c0]);
            sG[m][c1] = acc1[r] + __bfloat162float(xp[(size_t)m * 1280 + c1]);
        }
        __syncthreads();

        // nonlinearity + state update + publish (480 work items)
        for (int w = t; w < 480; w += 256) {
            int b = w / 30, jj = w % 30;
            float ig = sigmoidf_(sG[b][jj]);
            float fg = sigmoidf_(sG[b][30 + jj]);
            float gg = tanhf_(sG[b][60 + jj]);
            float og = sigmoidf_(sG[b][90 + jj]);
            float cn = fg * sC[b][jj] + ig * gg;
            sC[b][jj] = cn;
            float hv = og * tanhf_(cn);
            int gb = b0 + b;
            int jglob = g * 30 + jj;
            out[((size_t)gb * S_LEN + s) * 600 + dir * 300 + jglob] = hv;
            size_t ho = (((size_t)dir * 2 + (par ^ 1)) * 64 + gb) * 320 + jglob;
            __hip_bfloat16 hvh = __float2bfloat16(hv);
            hb_hi[ho] = hvh;
            hb_lo[ho] = __float2bfloat16(hv - __bfloat162float(hvh));
        }
        __syncthreads();   // all stores issued+drained (barrier drains vmcnt)

        // team barrier: release-add, acquire-spin, then invalidate stale caches
        cnt_target += G_SPLIT;
        if (t == 0) {
            __hip_atomic_fetch_add(myctr, 1, __ATOMIC_RELEASE, __HIP_MEMORY_SCOPE_AGENT);
            while (__hip_atomic_load(myctr, __ATOMIC_ACQUIRE, __HIP_MEMORY_SCOPE_AGENT) < cnt_target)
                __builtin_amdgcn_s_sleep(2);
        }
        __syncthreads();
        __threadfence();   // every wave: inv L1/L2 so fresh teammate h is visible
    }
}

// ---------------------------------------------------------------------------
extern "C" void kernel_launch(void* const* d_in, const int* in_sizes, int n_in,
                              void* d_out, int out_size, void* d_ws, size_t ws_size,
                              hipStream_t stream) {
    const int*   cf    = (const int*)d_in[0];
    const int*   bl    = (const int*)d_in[1];
    const int*   br    = (const int*)d_in[2];
    const int*   scf   = (const int*)d_in[3];
    const int*   sbl   = (const int*)d_in[4];
    const int*   sbr   = (const int*)d_in[5];
    const float* ce    = (const float*)d_in[6];
    const float* be    = (const float*)d_in[7];
    const float* sce   = (const float*)d_in[8];
    const float* sbe   = (const float*)d_in[9];
    const float* Wlin  = (const float*)d_in[10];
    const float* blin  = (const float*)d_in[11];
    const float* Wih_l = (const float*)d_in[12];
    const float* Whh_l = (const float*)d_in[13];
    const float* b_l   = (const float*)d_in[14];
    const float* Wih_r = (const float*)d_in[15];
    const float* Whh_r = (const float*)d_in[16];
    const float* b_r   = (const float*)d_in[17];
    float* out = (float*)d_out;

    // Workspace layout (bytes):
    //   A bf16   [2][32768][320] :  41,943,040
    //   X bf16   [2][512][64][1280] : 167,772,160
    //   Whh_p bf16 [2][1280][320] : 1,638,400
    //   Wih_p bf16 [2][1280][320] : 1,638,400
    //   bias_p f32 [2][1280]      : 10,240
    //   hb_hi/lo bf16 [2][2][64][320] x2 : 655,360
    //   ctr int [8] (+pad)        : 64
    //   total ~213.7 MB
    char* ws = (char*)d_ws;
    __hip_bfloat16* A_b    = (__hip_bfloat16*)(ws);
    __hip_bfloat16* A_l    = A_b;
    __hip_bfloat16* A_r    = A_b + (size_t)32768 * 320;
    __hip_bfloat16* X      = (__hip_bfloat16*)(ws + 41943040);
    __hip_bfloat16* Whh_p  = (__hip_bfloat16*)(ws + 209715200);
    __hip_bfloat16* Wih_p  = (__hip_bfloat16*)(ws + 211353600);
    float*          bias_p = (float*)(ws + 212992000);
    __hip_bfloat16* hb_hi  = (__hip_bfloat16*)(ws + 213002240);
    __hip_bfloat16* hb_lo  = (__hip_bfloat16*)(ws + 213329920);
    int*            ctr    = (int*)(ws + 213657600);

    k_prep_w<<<dim3((2 * 1280 * 320 + 255) / 256), dim3(256), 0, stream>>>(
        Whh_l, Whh_r, Wih_l, Wih_r, Whh_p, Wih_p);
    k_prep_misc<<<dim3(640), dim3(256), 0, stream>>>(b_l, b_r, hb_hi, hb_lo, bias_p, ctr);
    k_lin<<<dim3(512, 5, 2), dim3(256), 0, stream>>>(cf, bl, br, scf, sbl, sbr,
                                                     ce, be, sce, sbe, Wlin, blin,
                                                     A_l, A_r);
    k_xgemm<<<dim3(512, 10, 2), dim3(256), 0, stream>>>(A_b, Wih_p, bias_p, X);
    k_rec<<<dim3(80), dim3(256), 0, stream>>>(X, Whh_p, hb_hi, hb_lo, ctr, out);
}

// Round 3
// 4312.025 us; speedup vs baseline: 2.4763x; 1.7465x over previous
//
#include <hip/hip_runtime.h>
#include <hip/hip_bf16.h>

// Problem constants
#define S_LEN 512
#define BATCH 64
#define DC    200
#define HID   300
#define H4    1200
#define IN_DIM 800
#define G_SPLIT 10          // gate-blocks per recurrence team (30 h-dims each)

typedef __attribute__((ext_vector_type(8))) short short8b;   // 8 bf16
typedef __attribute__((ext_vector_type(4))) float f32x4;

__device__ __forceinline__ float sigmoidf_(float x) { return 1.0f / (1.0f + __expf(-x)); }
__device__ __forceinline__ float tanhf_(float x)    { return 2.0f / (1.0f + __expf(-2.0f * x)) - 1.0f; }

// ---------------------------------------------------------------------------
// Permuted weight prep. Gate rows reordered so block g owns rows
// [g*128, g*128+128): locals 0..119 = {i,f,g,o} x 30 h-dims (j = g*30+jj),
// locals 120..127 zero pad. K padded 300->320 with zeros. bf16.
// ---------------------------------------------------------------------------
__global__ void k_prep_w(const float* __restrict__ Whh_l, const float* __restrict__ Whh_r,
                         const float* __restrict__ Wih_l, const float* __restrict__ Wih_r,
                         __hip_bfloat16* __restrict__ Whh_p, __hip_bfloat16* __restrict__ Wih_p) {
    int i = blockIdx.x * 256 + threadIdx.x;        // over 2*1280*320
    if (i >= 2 * 1280 * 320) return;
    int k = i % 320;
    int R = (i / 320) % 1280;
    int d = i / (320 * 1280);
    int g = R >> 7, local = R & 127;
    float vh = 0.f, vi = 0.f;
    if (local < 120 && k < 300) {
        int q = local / 30, jj = local % 30;
        int n = q * 300 + g * 30 + jj;
        const float* Whh = d ? Whh_r : Whh_l;
        const float* Wih = d ? Wih_r : Wih_l;
        vh = Whh[n * 300 + k];
        vi = Wih[n * 300 + k];
    }
    Whh_p[i] = __float2bfloat16(vh);
    Wih_p[i] = __float2bfloat16(vi);
}

// Zero h-buffer + counters, build permuted bias. Runs every launch (graph replays).
__global__ void k_prep_misc(const float* __restrict__ b_l, const float* __restrict__ b_r,
                            float* __restrict__ hbuf,       // [2][2][64][320] f32
                            float* __restrict__ bias_p, int* __restrict__ ctr) {
    int i = blockIdx.x * 256 + threadIdx.x;
    if (i < 2 * 2 * 64 * 320) hbuf[i] = 0.f;
    if (i < 2 * 1280) {
        int d = i / 1280, R = i % 1280;
        int g = R >> 7, local = R & 127;
        float v = 0.f;
        if (local < 120) { int q = local / 30, jj = local % 30; v = (d ? b_r : b_l)[q * 300 + g * 30 + jj]; }
        bias_p[i] = v;
    }
    if (i < 8) ctr[i] = 0;
}

// ---------------------------------------------------------------------------
// K1: fused embedding-gather + linear + tanh (f32 compute, bf16 out, stride 320)
// ---------------------------------------------------------------------------
__global__ __launch_bounds__(256) void k_lin(
    const int* __restrict__ cf, const int* __restrict__ bl, const int* __restrict__ br,
    const int* __restrict__ scf, const int* __restrict__ sbl, const int* __restrict__ sbr,
    const float* __restrict__ ce, const float* __restrict__ be,
    const float* __restrict__ sce, const float* __restrict__ sbe,
    const float* __restrict__ W, const float* __restrict__ bias,
    __hip_bfloat16* __restrict__ outL, __hip_bfloat16* __restrict__ outR)
{
    const int z = blockIdx.z;
    const int* dynIdx  = z ? br  : bl;
    const int* statIdx = z ? sbr : sbl;
    __hip_bfloat16* outp = z ? outR : outL;
    const int m0 = blockIdx.x * 64;
    const int n0 = blockIdx.y * 64;
    __shared__ float As[16][68];
    __shared__ float Bs[16][68];
    const int t  = threadIdx.x;
    const int lk = t & 15;
    const int lm = t >> 4;
    const int tx = t & 15, ty = t >> 4;
    float acc[4][4] = {};

    for (int k0 = 0; k0 < IN_DIM; k0 += 16) {
        const int kk  = k0 + lk;
        const int seg = kk / 200;
        const int kin = kk - seg * 200;
        const int*   idxA = (seg == 0) ? cf : (seg == 1) ? scf : (seg == 2) ? dynIdx : statIdx;
        const float* tab  = (seg == 0) ? ce : (seg == 1) ? sce : (seg == 2) ? be     : sbe;
#pragma unroll
        for (int r = 0; r < 4; ++r) {
            int m = m0 + lm + r * 16;
            int id = idxA[m];
            As[lk][lm + r * 16] = tab[(size_t)id * DC + kin];
        }
#pragma unroll
        for (int r = 0; r < 4; ++r) {
            int n = n0 + lm + r * 16;
            Bs[lk][lm + r * 16] = (n < HID) ? W[n * IN_DIM + kk] : 0.f;
        }
        __syncthreads();
#pragma unroll
        for (int kq = 0; kq < 16; ++kq) {
            float a[4], b[4];
#pragma unroll
            for (int i = 0; i < 4; ++i) a[i] = As[kq][ty * 4 + i];
#pragma unroll
            for (int j = 0; j < 4; ++j) b[j] = Bs[kq][tx * 4 + j];
#pragma unroll
            for (int i = 0; i < 4; ++i)
#pragma unroll
                for (int j = 0; j < 4; ++j) acc[i][j] = fmaf(a[i], b[j], acc[i][j]);
        }
        __syncthreads();
    }
#pragma unroll
    for (int i = 0; i < 4; ++i) {
        int m = m0 + ty * 4 + i;
#pragma unroll
        for (int j = 0; j < 4; ++j) {
            int n = n0 + tx * 4 + j;
            float v = (n < HID) ? tanhf_(acc[i][j] + bias[n]) : 0.f;   // zero K-pad 300..319
            outp[(size_t)m * 320 + n] = __float2bfloat16(v);
        }
    }
}

// ---------------------------------------------------------------------------
// K2: X = A @ Wih_p^T + bias_p, bf16 MFMA 16x16x32.
// ---------------------------------------------------------------------------
__global__ __launch_bounds__(256) void k_xgemm(
    const __hip_bfloat16* __restrict__ A,
    const __hip_bfloat16* __restrict__ Wih_p,
    const float* __restrict__ bias_p,
    __hip_bfloat16* __restrict__ Xout)
{
    const int dir = blockIdx.z;
    const int m0 = blockIdx.x * 64;
    const int n0 = blockIdx.y * 128;
    const __hip_bfloat16* Ad = A + (size_t)dir * 32768 * 320;
    const __hip_bfloat16* Wd = Wih_p + (size_t)dir * 1280 * 320;
    const float* bd = bias_p + dir * 1280;
    __hip_bfloat16* Xd = Xout + (size_t)dir * 512 * 64 * 1280;

    __shared__ __hip_bfloat16 sA[64][40];
    __shared__ __hip_bfloat16 sB[128][40];
    const int t = threadIdx.x, lane = t & 63, wv = t >> 6;
    f32x4 acc[4][2] = {};

    for (int k0 = 0; k0 < 320; k0 += 32) {
        {
            int r = t >> 2, kg = (t & 3) * 8;
            *reinterpret_cast<short8b*>(&sA[r][kg]) =
                *reinterpret_cast<const short8b*>(Ad + (size_t)(m0 + r) * 320 + k0 + kg);
        }
#pragma unroll
        for (int i = 0; i < 2; ++i) {
            int c = t + i * 256;
            int r = c >> 2, kg = (c & 3) * 8;
            *reinterpret_cast<short8b*>(&sB[r][kg]) =
                *reinterpret_cast<const short8b*>(Wd + (size_t)(n0 + r) * 320 + k0 + kg);
        }
        __syncthreads();
        const int kl = (lane >> 4) * 8;
#pragma unroll
        for (int mt = 0; mt < 4; ++mt) {
            short8b af = *reinterpret_cast<const short8b*>(&sA[mt * 16 + (lane & 15)][kl]);
#pragma unroll
            for (int nt = 0; nt < 2; ++nt) {
                short8b bf = *reinterpret_cast<const short8b*>(&sB[(wv * 2 + nt) * 16 + (lane & 15)][kl]);
                acc[mt][nt] = __builtin_amdgcn_mfma_f32_16x16x32_bf16(af, bf, acc[mt][nt], 0, 0, 0);
            }
        }
        __syncthreads();
    }
#pragma unroll
    for (int mt = 0; mt < 4; ++mt)
#pragma unroll
        for (int nt = 0; nt < 2; ++nt) {
            int p = n0 + (wv * 2 + nt) * 16 + (lane & 15);
            float bv = bd[p];
#pragma unroll
            for (int r = 0; r < 4; ++r) {
                int m = m0 + mt * 16 + (lane >> 4) * 4 + r;
                int b = m >> 9, s = m & 511;
                Xd[(size_t)(s * 64 + b) * 1280 + p] = __float2bfloat16(acc[mt][nt][r] + bv);
            }
        }
}

// ---------------------------------------------------------------------------
// K3: LSTM recurrence — weight-stationary teams, FENCE-FREE h exchange.
// 80 blocks = 2 dirs x 4 batch-groups(16) x 10 gate-blocks. Whh slice in LDS.
// h exchanged as f32 via RELAXED agent-scope atomics (per-access coherence,
// no L2 flush). Barrier: vmcnt(0) drain -> relaxed counter add -> relaxed spin.
// ---------------------------------------------------------------------------
__global__ __launch_bounds__(256) void k_rec(
    const __hip_bfloat16* __restrict__ X,      // [2][512][64][1280]
    const __hip_bfloat16* __restrict__ Whh_p,  // [2][1280][320]
    float* __restrict__ hbuf,                  // [2][2][64][320] f32, parity dbuf
    int* __restrict__ ctr,                     // [8] per-team monotonic counters
    float* __restrict__ out)                   // [64][512][600]
{
    const int bid = blockIdx.x;
    const int dir = bid / (4 * G_SPLIT);
    const int grp = (bid / G_SPLIT) % 4;
    const int g   = bid % G_SPLIT;
    const int t = threadIdx.x;
    const int lane = t & 63, wv = t >> 6;
    const int b0 = grp * 16;

    __shared__ __hip_bfloat16 sW[128][328];
    __shared__ __hip_bfloat16 sHi[16][328];
    __shared__ __hip_bfloat16 sLo[16][328];
    __shared__ float sG[16][128];
    __shared__ float sC[16][32];

    const __hip_bfloat16* Wsrc = Whh_p + ((size_t)dir * 1280 + g * 128) * 320;
    for (int i = t; i < 128 * 40; i += 256) {
        int r = i / 40, kg = (i % 40) * 8;
        *reinterpret_cast<short8b*>(&sW[r][kg]) = *reinterpret_cast<const short8b*>(Wsrc + r * 320 + kg);
    }
    for (int i = t; i < 16 * 32; i += 256) sC[i >> 5][i & 31] = 0.f;
    __syncthreads();

    int* myctr = ctr + dir * 4 + grp;
    int cnt_target = 0;
    const int n0 = wv * 32;
    const int kl = (lane >> 4) * 8;
    const int bb = lane & 15;
    const int hb = t >> 4;           // h-load: batch row 0..15
    const int kc = (t & 15) * 20;    // h-load: k chunk start

    for (int tau = 0; tau < S_LEN; ++tau) {
        const int s = dir ? (S_LEN - 1 - tau) : tau;
        const int par = tau & 1;

        // 1) coherent h load (f32 @ L3) -> split hi/lo bf16 -> LDS
        {
            const unsigned long long* hrow = reinterpret_cast<const unsigned long long*>(
                hbuf + (((size_t)dir * 2 + par) * 64 + b0 + hb) * 320 + kc);
#pragma unroll
            for (int i = 0; i < 10; ++i) {
                unsigned long long v = __hip_atomic_load(hrow + i, __ATOMIC_RELAXED, __HIP_MEMORY_SCOPE_AGENT);
                float f0 = __uint_as_float((unsigned)(v & 0xffffffffu));
                float f1 = __uint_as_float((unsigned)(v >> 32));
                __hip_bfloat16 h0 = __float2bfloat16(f0);
                __hip_bfloat16 h1 = __float2bfloat16(f1);
                sHi[hb][kc + 2 * i]     = h0;
                sHi[hb][kc + 2 * i + 1] = h1;
                sLo[hb][kc + 2 * i]     = __float2bfloat16(f0 - __bfloat162float(h0));
                sLo[hb][kc + 2 * i + 1] = __float2bfloat16(f1 - __bfloat162float(h1));
            }
        }

        // X prefetch (plain cached loads) -> accumulator init
        const __hip_bfloat16* xp = X + (((size_t)dir * 512 + s) * 64 + b0) * 1280 + g * 128;
        f32x4 acc0, acc1;
#pragma unroll
        for (int r = 0; r < 4; ++r) {
            int m = (lane >> 4) * 4 + r;
            acc0[r] = __bfloat162float(xp[(size_t)m * 1280 + n0 + bb]);
            acc1[r] = __bfloat162float(xp[(size_t)m * 1280 + n0 + 16 + bb]);
        }
        __syncthreads();

        // 2) gates = X + h_hi @ W + h_lo @ W
        for (int kt = 0; kt < 10; ++kt) {
            short8b ahi = *reinterpret_cast<const short8b*>(&sHi[bb][kt * 32 + kl]);
            short8b alo = *reinterpret_cast<const short8b*>(&sLo[bb][kt * 32 + kl]);
            short8b bf0 = *reinterpret_cast<const short8b*>(&sW[n0 + bb][kt * 32 + kl]);
            short8b bf1 = *reinterpret_cast<const short8b*>(&sW[n0 + 16 + bb][kt * 32 + kl]);
            acc0 = __builtin_amdgcn_mfma_f32_16x16x32_bf16(ahi, bf0, acc0, 0, 0, 0);
            acc1 = __builtin_amdgcn_mfma_f32_16x16x32_bf16(ahi, bf1, acc1, 0, 0, 0);
            acc0 = __builtin_amdgcn_mfma_f32_16x16x32_bf16(alo, bf0, acc0, 0, 0, 0);
            acc1 = __builtin_amdgcn_mfma_f32_16x16x32_bf16(alo, bf1, acc1, 0, 0, 0);
        }
#pragma unroll
        for (int r = 0; r < 4; ++r) {
            int m = (lane >> 4) * 4 + r;
            sG[m][n0 + bb] = acc0[r];
            sG[m][n0 + 16 + bb] = acc1[r];
        }
        __syncthreads();

        // 3) nonlinearity + state update + publish h (relaxed agent stores)
        for (int w = t; w < 480; w += 256) {
            int b = w / 30, jj = w % 30;
            float ig = sigmoidf_(sG[b][jj]);
            float fg = sigmoidf_(sG[b][30 + jj]);
            float gg = tanhf_(sG[b][60 + jj]);
            float og = sigmoidf_(sG[b][90 + jj]);
            float cn = fg * sC[b][jj] + ig * gg;
            sC[b][jj] = cn;
            float hv = og * tanhf_(cn);
            int gb = b0 + b;
            int jglob = g * 30 + jj;
            out[((size_t)gb * S_LEN + s) * 600 + dir * 300 + jglob] = hv;
            __hip_atomic_store(hbuf + (((size_t)dir * 2 + (par ^ 1)) * 64 + gb) * 320 + jglob,
                               hv, __ATOMIC_RELAXED, __HIP_MEMORY_SCOPE_AGENT);
        }
        // release: drain own stores to coherence point, then all threads arrive
        asm volatile("s_waitcnt vmcnt(0)" ::: "memory");
        __syncthreads();

        // team barrier: relaxed add + relaxed spin (no L2 writeback/invalidate)
        cnt_target += G_SPLIT;
        if (t == 0) {
            __hip_atomic_fetch_add(myctr, 1, __ATOMIC_RELAXED, __HIP_MEMORY_SCOPE_AGENT);
            while (__hip_atomic_load(myctr, __ATOMIC_RELAXED, __HIP_MEMORY_SCOPE_AGENT) < cnt_target)
                __builtin_amdgcn_s_sleep(1);
        }
        __syncthreads();
    }
}

// ---------------------------------------------------------------------------
extern "C" void kernel_launch(void* const* d_in, const int* in_sizes, int n_in,
                              void* d_out, int out_size, void* d_ws, size_t ws_size,
                              hipStream_t stream) {
    const int*   cf    = (const int*)d_in[0];
    const int*   bl    = (const int*)d_in[1];
    const int*   br    = (const int*)d_in[2];
    const int*   scf   = (const int*)d_in[3];
    const int*   sbl   = (const int*)d_in[4];
    const int*   sbr   = (const int*)d_in[5];
    const float* ce    = (const float*)d_in[6];
    const float* be    = (const float*)d_in[7];
    const float* sce   = (const float*)d_in[8];
    const float* sbe   = (const float*)d_in[9];
    const float* Wlin  = (const float*)d_in[10];
    const float* blin  = (const float*)d_in[11];
    const float* Wih_l = (const float*)d_in[12];
    const float* Whh_l = (const float*)d_in[13];
    const float* b_l   = (const float*)d_in[14];
    const float* Wih_r = (const float*)d_in[15];
    const float* Whh_r = (const float*)d_in[16];
    const float* b_r   = (const float*)d_in[17];
    float* out = (float*)d_out;

    // Workspace layout (bytes):
    //   A bf16   [2][32768][320]     :  41,943,040
    //   X bf16   [2][512][64][1280]  : 167,772,160  (ends 209,715,200)
    //   Whh_p bf16 [2][1280][320]    :   1,638,400  (ends 211,353,600)
    //   Wih_p bf16 [2][1280][320]    :   1,638,400  (ends 212,992,000)
    //   bias_p f32 [2][1280]         :      10,240  (ends 213,002,240)
    //   hbuf f32 [2][2][64][320]     :   1,310,720  (ends 214,312,960)
    //   ctr int [8]                  :          64
    char* ws = (char*)d_ws;
    __hip_bfloat16* A_b    = (__hip_bfloat16*)(ws);
    __hip_bfloat16* A_l    = A_b;
    __hip_bfloat16* A_r    = A_b + (size_t)32768 * 320;
    __hip_bfloat16* X      = (__hip_bfloat16*)(ws + 41943040);
    __hip_bfloat16* Whh_p  = (__hip_bfloat16*)(ws + 209715200);
    __hip_bfloat16* Wih_p  = (__hip_bfloat16*)(ws + 211353600);
    float*          bias_p = (float*)(ws + 212992000);
    float*          hbuf   = (float*)(ws + 213002240);
    int*            ctr    = (int*)(ws + 214312960);

    k_prep_w<<<dim3((2 * 1280 * 320 + 255) / 256), dim3(256), 0, stream>>>(
        Whh_l, Whh_r, Wih_l, Wih_r, Whh_p, Wih_p);
    k_prep_misc<<<dim3(1280), dim3(256), 0, stream>>>(b_l, b_r, hbuf, bias_p, ctr);
    k_lin<<<dim3(512, 5, 2), dim3(256), 0, stream>>>(cf, bl, br, scf, sbl, sbr,
                                                     ce, be, sce, sbe, Wlin, blin,
                                                     A_l, A_r);
    k_xgemm<<<dim3(512, 10, 2), dim3(256), 0, stream>>>(A_b, Wih_p, bias_p, X);
    k_rec<<<dim3(80), dim3(256), 0, stream>>>(X, Whh_p, hbuf, ctr, out);
}

// Round 4
// 3143.865 us; speedup vs baseline: 3.3964x; 1.3716x over previous
//
#include <hip/hip_runtime.h>
#include <hip/hip_bf16.h>

// Problem constants
#define S_LEN 512
#define BATCH 64
#define DC    200
#define HID   300
#define H4    1200
#define IN_DIM 800
#define G_SPLIT 10          // gate-blocks per recurrence team (30 h-dims each)

typedef __attribute__((ext_vector_type(8))) short short8b;   // 8 bf16
typedef __attribute__((ext_vector_type(4))) float f32x4;

__device__ __forceinline__ float sigmoidf_(float x) { return 1.0f / (1.0f + __expf(-x)); }
__device__ __forceinline__ float tanhf_(float x)    { return 2.0f / (1.0f + __expf(-2.0f * x)) - 1.0f; }

// ---------------------------------------------------------------------------
// Weight prep. Gate-row permutation: block g owns rows [g*128, g*128+128):
// locals 0..119 = {i,f,g,o} x 30 h-dims (j = g*30+jj), 120..127 zero pad.
// Whh additionally k-PERMUTED: k-slot = g2*32 + jj2  <->  h-dim g2*30 + jj2
// (slots with jj2>=30 are zero) so h exchange is 16B-chunk aligned per block.
// Wih keeps plain k 0..299 (+20 pad).
// ---------------------------------------------------------------------------
__global__ void k_prep_w(const float* __restrict__ Whh_l, const float* __restrict__ Whh_r,
                         const float* __restrict__ Wih_l, const float* __restrict__ Wih_r,
                         __hip_bfloat16* __restrict__ Whh_p, __hip_bfloat16* __restrict__ Wih_p) {
    int i = blockIdx.x * 256 + threadIdx.x;        // over 2*1280*320
    if (i >= 2 * 1280 * 320) return;
    int slot = i % 320;
    int R = (i / 320) % 1280;
    int d = i / (320 * 1280);
    int g = R >> 7, local = R & 127;
    float vh = 0.f, vi = 0.f;
    if (local < 120) {
        int q = local / 30, jj = local % 30;
        int n = q * 300 + g * 30 + jj;
        const float* Whh = d ? Whh_r : Whh_l;
        const float* Wih = d ? Wih_r : Wih_l;
        int g2 = slot >> 5, jj2 = slot & 31;
        if (jj2 < 30) vh = Whh[n * 300 + g2 * 30 + jj2];
        if (slot < 300) vi = Wih[n * 300 + slot];
    }
    Whh_p[i] = __float2bfloat16(vh);
    Wih_p[i] = __float2bfloat16(vi);
}

// Zero h-buffers + counters, build permuted bias. Runs every launch.
__global__ void k_prep_misc(const float* __restrict__ b_l, const float* __restrict__ b_r,
                            __hip_bfloat16* __restrict__ hb_hi, __hip_bfloat16* __restrict__ hb_lo,
                            float* __restrict__ bias_p, int* __restrict__ ctr) {
    int i = blockIdx.x * 256 + threadIdx.x;
    if (i < 2 * 2 * 64 * 320) {
        hb_hi[i] = __float2bfloat16(0.f);
        hb_lo[i] = __float2bfloat16(0.f);
    }
    if (i < 2 * 1280) {
        int d = i / 1280, R = i % 1280;
        int g = R >> 7, local = R & 127;
        float v = 0.f;
        if (local < 120) { int q = local / 30, jj = local % 30; v = (d ? b_r : b_l)[q * 300 + g * 30 + jj]; }
        bias_p[i] = v;
    }
    if (i < 8) ctr[i] = 0;
}

// ---------------------------------------------------------------------------
// K1: fused embedding-gather + linear + tanh, bf16 MFMA, BN=320 (full N).
// Grid (512 m-tiles, 2 dirs). Each table row gathered exactly once per dir.
// ---------------------------------------------------------------------------
__global__ __launch_bounds__(256) void k_lin(
    const int* __restrict__ cf, const int* __restrict__ bl, const int* __restrict__ br,
    const int* __restrict__ scf, const int* __restrict__ sbl, const int* __restrict__ sbr,
    const float* __restrict__ ce, const float* __restrict__ be,
    const float* __restrict__ sce, const float* __restrict__ sbe,
    const float* __restrict__ W, const float* __restrict__ bias,
    __hip_bfloat16* __restrict__ outL, __hip_bfloat16* __restrict__ outR)
{
    const int z = blockIdx.y;
    const int* dynIdx  = z ? br  : bl;
    const int* statIdx = z ? sbr : sbl;
    __hip_bfloat16* outp = z ? outR : outL;
    const int m0 = blockIdx.x * 64;

    __shared__ __align__(16) __hip_bfloat16 sA[64][40];
    __shared__ __align__(16) __hip_bfloat16 sB[320][40];
    const int t = threadIdx.x, lane = t & 63, wv = t >> 6;

    const int rA = t >> 2, c8A = (t & 3) * 8;
    const int mA = m0 + rA;
    const int idc = cf[mA], idsc = scf[mA], idd = dynIdx[mA], ids = statIdx[mA];

    f32x4 acc[4][5] = {};

    for (int k0 = 0; k0 < IN_DIM; k0 += 32) {
        {   // A stage: gather 8 f32 from the right table, cvt bf16
            int k = k0 + c8A;
            int seg = k / 200, kin = k - seg * 200;
            const float* tab = (seg == 0) ? ce : (seg == 1) ? sce : (seg == 2) ? be : sbe;
            int id = (seg == 0) ? idc : (seg == 1) ? idsc : (seg == 2) ? idd : ids;
            const float* tp = tab + (size_t)id * DC + kin;
            f32x4 v0 = *reinterpret_cast<const f32x4*>(tp);
            f32x4 v1 = *reinterpret_cast<const f32x4*>(tp + 4);
            union { short8b v; __hip_bfloat16 h[8]; } u;
#pragma unroll
            for (int q = 0; q < 4; ++q) { u.h[q] = __float2bfloat16(v0[q]); u.h[4 + q] = __float2bfloat16(v1[q]); }
            *reinterpret_cast<short8b*>(&sA[rA][c8A]) = u.v;
        }
#pragma unroll
        for (int j = 0; j < 5; ++j) {   // B stage: 320 rows x 4 chunks
            int i = t + j * 256;
            int n = i >> 2, ch = (i & 3) * 8;
            f32x4 v0 = {0, 0, 0, 0}, v1 = {0, 0, 0, 0};
            if (n < HID) {
                const float* wp = W + (size_t)n * IN_DIM + k0 + ch;
                v0 = *reinterpret_cast<const f32x4*>(wp);
                v1 = *reinterpret_cast<const f32x4*>(wp + 4);
            }
            union { short8b v; __hip_bfloat16 h[8]; } u;
#pragma unroll
            for (int q = 0; q < 4; ++q) { u.h[q] = __float2bfloat16(v0[q]); u.h[4 + q] = __float2bfloat16(v1[q]); }
            *reinterpret_cast<short8b*>(&sB[n][ch]) = u.v;
        }
        __syncthreads();
        const int kl = (lane >> 4) * 8, bb = lane & 15;
#pragma unroll
        for (int mt = 0; mt < 4; ++mt) {
            short8b af = *reinterpret_cast<const short8b*>(&sA[mt * 16 + bb][kl]);
#pragma unroll
            for (int nt = 0; nt < 5; ++nt) {
                short8b bf = *reinterpret_cast<const short8b*>(&sB[(wv * 5 + nt) * 16 + bb][kl]);
                acc[mt][nt] = __builtin_amdgcn_mfma_f32_16x16x32_bf16(af, bf, acc[mt][nt], 0, 0, 0);
            }
        }
        __syncthreads();
    }
    const int bb = lane & 15;
#pragma unroll
    for (int mt = 0; mt < 4; ++mt)
#pragma unroll
        for (int nt = 0; nt < 5; ++nt) {
            int p = (wv * 5 + nt) * 16 + bb;
            float bv = (p < HID) ? bias[p] : 0.f;
#pragma unroll
            for (int r = 0; r < 4; ++r) {
                int m = m0 + mt * 16 + (lane >> 4) * 4 + r;
                float val = (p < HID) ? tanhf_(acc[mt][nt][r] + bv) : 0.f;
                outp[(size_t)m * 320 + p] = __float2bfloat16(val);
            }
        }
}

// ---------------------------------------------------------------------------
// K2: X = A @ Wih_p^T + bias_p, bf16 MFMA 16x16x32 (unchanged from R3).
// ---------------------------------------------------------------------------
__global__ __launch_bounds__(256) void k_xgemm(
    const __hip_bfloat16* __restrict__ A,
    const __hip_bfloat16* __restrict__ Wih_p,
    const float* __restrict__ bias_p,
    __hip_bfloat16* __restrict__ Xout)
{
    const int dir = blockIdx.z;
    const int m0 = blockIdx.x * 64;
    const int n0 = blockIdx.y * 128;
    const __hip_bfloat16* Ad = A + (size_t)dir * 32768 * 320;
    const __hip_bfloat16* Wd = Wih_p + (size_t)dir * 1280 * 320;
    const float* bd = bias_p + dir * 1280;
    __hip_bfloat16* Xd = Xout + (size_t)dir * 512 * 64 * 1280;

    __shared__ __align__(16) __hip_bfloat16 sA[64][40];
    __shared__ __align__(16) __hip_bfloat16 sB[128][40];
    const int t = threadIdx.x, lane = t & 63, wv = t >> 6;
    f32x4 acc[4][2] = {};

    for (int k0 = 0; k0 < 320; k0 += 32) {
        {
            int r = t >> 2, kg = (t & 3) * 8;
            *reinterpret_cast<short8b*>(&sA[r][kg]) =
                *reinterpret_cast<const short8b*>(Ad + (size_t)(m0 + r) * 320 + k0 + kg);
        }
#pragma unroll
        for (int i = 0; i < 2; ++i) {
            int c = t + i * 256;
            int r = c >> 2, kg = (c & 3) * 8;
            *reinterpret_cast<short8b*>(&sB[r][kg]) =
                *reinterpret_cast<const short8b*>(Wd + (size_t)(n0 + r) * 320 + k0 + kg);
        }
        __syncthreads();
        const int kl = (lane >> 4) * 8;
#pragma unroll
        for (int mt = 0; mt < 4; ++mt) {
            short8b af = *reinterpret_cast<const short8b*>(&sA[mt * 16 + (lane & 15)][kl]);
#pragma unroll
            for (int nt = 0; nt < 2; ++nt) {
                short8b bf = *reinterpret_cast<const short8b*>(&sB[(wv * 2 + nt) * 16 + (lane & 15)][kl]);
                acc[mt][nt] = __builtin_amdgcn_mfma_f32_16x16x32_bf16(af, bf, acc[mt][nt], 0, 0, 0);
            }
        }
        __syncthreads();
    }
#pragma unroll
    for (int mt = 0; mt < 4; ++mt)
#pragma unroll
        for (int nt = 0; nt < 2; ++nt) {
            int p = n0 + (wv * 2 + nt) * 16 + (lane & 15);
            float bv = bd[p];
#pragma unroll
            for (int r = 0; r < 4; ++r) {
                int m = m0 + mt * 16 + (lane >> 4) * 4 + r;
                int b = m >> 9, s = m & 511;
                Xd[(size_t)(s * 64 + b) * 1280 + p] = __float2bfloat16(acc[mt][nt][r] + bv);
            }
        }
}

// ---------------------------------------------------------------------------
// K3: LSTM recurrence — weight-stationary teams, vectorized coherent exchange.
// h lives in hb_hi/hb_lo bf16 [dir][par][64][320], k-slot g*32+jj (producer-split).
// Consumer: 5x global_load_dwordx4 sc0 sc1 per thread -> ds_write_b128 (no cvt).
// Producer: stage hi/lo in LDS -> 128 x 16B coherent stores.
// X(t+1) prefetched before the barrier.
// ---------------------------------------------------------------------------
__global__ __launch_bounds__(256) void k_rec(
    const __hip_bfloat16* __restrict__ X,      // [2][512][64][1280]
    const __hip_bfloat16* __restrict__ Whh_p,  // [2][1280][320] (k-permuted)
    __hip_bfloat16* __restrict__ hb_hi,        // [2][2][64][320]
    __hip_bfloat16* __restrict__ hb_lo,
    int* __restrict__ ctr,                     // [8]
    float* __restrict__ out)                   // [64][512][600]
{
    const int bid = blockIdx.x;
    const int dir = bid / (4 * G_SPLIT);
    const int grp = (bid / G_SPLIT) % 4;
    const int g   = bid % G_SPLIT;
    const int t = threadIdx.x;
    const int lane = t & 63, wv = t >> 6;
    const int b0 = grp * 16;

    __shared__ __align__(16) __hip_bfloat16 sW[128][328];
    __shared__ __align__(16) __hip_bfloat16 sHi[16][328];
    __shared__ __align__(16) __hip_bfloat16 sLo[16][328];
    __shared__ float sG[16][128];
    __shared__ float sC[16][32];
    __shared__ __align__(16) __hip_bfloat16 sPub[2][16][32];

    const __hip_bfloat16* Wsrc = Whh_p + ((size_t)dir * 1280 + g * 128) * 320;
    for (int i = t; i < 128 * 40; i += 256) {
        int r = i / 40, kg = (i % 40) * 8;
        *reinterpret_cast<short8b*>(&sW[r][kg]) = *reinterpret_cast<const short8b*>(Wsrc + r * 320 + kg);
    }
    for (int i = t; i < 16 * 32; i += 256) sC[i >> 5][i & 31] = 0.f;
    __syncthreads();

    int* myctr = ctr + dir * 4 + grp;
    int cnt_target = 0;
    const int n0 = wv * 32;
    const int kl = (lane >> 4) * 8;
    const int bb = lane & 15;

    // X prefetch registers (8 bf16 per thread)
    __hip_bfloat16 xa[8];
    {
        const int s0 = dir ? (S_LEN - 1) : 0;
        const __hip_bfloat16* xp = X + (((size_t)dir * 512 + s0) * 64 + b0) * 1280 + g * 128;
#pragma unroll
        for (int r = 0; r < 4; ++r) {
            int m = (lane >> 4) * 4 + r;
            xa[r]     = xp[(size_t)m * 1280 + n0 + bb];
            xa[4 + r] = xp[(size_t)m * 1280 + n0 + 16 + bb];
        }
    }

    for (int tau = 0; tau < S_LEN; ++tau) {
        const int s = dir ? (S_LEN - 1 - tau) : tau;
        const int par = tau & 1;

        // 1) coherent h load (1280 x 16B chunks, 5/thread) -> LDS, no conversion
        f32x4 hv[5];
#pragma unroll
        for (int j = 0; j < 5; ++j) {
            int i = t + j * 256;
            int buf = i / 640, ii = i % 640;
            int r = ii / 40, ch = ii % 40;
            const __hip_bfloat16* p = (buf ? hb_lo : hb_hi)
                + (((size_t)dir * 2 + par) * 64 + b0 + r) * 320 + ch * 8;
            asm volatile("global_load_dwordx4 %0, %1, off sc0 sc1"
                         : "=v"(hv[j]) : "v"(p) : "memory");
        }
        asm volatile("s_waitcnt vmcnt(0)" ::: "memory");
        __builtin_amdgcn_sched_barrier(0);
#pragma unroll
        for (int j = 0; j < 5; ++j) {
            int i = t + j * 256;
            int buf = i / 640, ii = i % 640;
            int r = ii / 40, ch = ii % 40;
            __hip_bfloat16* dst = buf ? &sLo[r][ch * 8] : &sHi[r][ch * 8];
            *reinterpret_cast<f32x4*>(dst) = hv[j];
        }
        __syncthreads();

        // 2) gates = X + h_hi @ W + h_lo @ W
        f32x4 acc0, acc1;
#pragma unroll
        for (int r = 0; r < 4; ++r) {
            acc0[r] = __bfloat162float(xa[r]);
            acc1[r] = __bfloat162float(xa[4 + r]);
        }
        for (int kt = 0; kt < 10; ++kt) {
            short8b ahi = *reinterpret_cast<const short8b*>(&sHi[bb][kt * 32 + kl]);
            short8b alo = *reinterpret_cast<const short8b*>(&sLo[bb][kt * 32 + kl]);
            short8b bf0 = *reinterpret_cast<const short8b*>(&sW[n0 + bb][kt * 32 + kl]);
            short8b bf1 = *reinterpret_cast<const short8b*>(&sW[n0 + 16 + bb][kt * 32 + kl]);
            acc0 = __builtin_amdgcn_mfma_f32_16x16x32_bf16(ahi, bf0, acc0, 0, 0, 0);
            acc1 = __builtin_amdgcn_mfma_f32_16x16x32_bf16(ahi, bf1, acc1, 0, 0, 0);
            acc0 = __builtin_amdgcn_mfma_f32_16x16x32_bf16(alo, bf0, acc0, 0, 0, 0);
            acc1 = __builtin_amdgcn_mfma_f32_16x16x32_bf16(alo, bf1, acc1, 0, 0, 0);
        }
#pragma unroll
        for (int r = 0; r < 4; ++r) {
            int m = (lane >> 4) * 4 + r;
            sG[m][n0 + bb] = acc0[r];
            sG[m][n0 + 16 + bb] = acc1[r];
        }
        __syncthreads();

        // 3) nonlinearity + state update + stage publish (512 items incl. pads)
#pragma unroll
        for (int w = t; w < 512; w += 256) {
            int b = w >> 5, jj = w & 31;
            __hip_bfloat16 hhi = __float2bfloat16(0.f), hlo = __float2bfloat16(0.f);
            if (jj < 30) {
                float ig = sigmoidf_(sG[b][jj]);
                float fg = sigmoidf_(sG[b][30 + jj]);
                float gg = tanhf_(sG[b][60 + jj]);
                float og = sigmoidf_(sG[b][90 + jj]);
                float cn = fg * sC[b][jj] + ig * gg;
                sC[b][jj] = cn;
                float hvv = og * tanhf_(cn);
                out[((size_t)(b0 + b) * S_LEN + s) * 600 + dir * 300 + g * 30 + jj] = hvv;
                hhi = __float2bfloat16(hvv);
                hlo = __float2bfloat16(hvv - __bfloat162float(hhi));
            }
            sPub[0][b][jj] = hhi;
            sPub[1][b][jj] = hlo;
        }
        __syncthreads();

        // 4) publish (128 x 16B coherent stores) + X(t+1) prefetch
        if (t < 128) {
            int buf = t >> 6, c = t & 63, r = c >> 2, ch = c & 3;
            f32x4 v = *reinterpret_cast<f32x4*>(&sPub[buf][r][ch * 8]);
            __hip_bfloat16* p = (buf ? hb_lo : hb_hi)
                + (((size_t)dir * 2 + (par ^ 1)) * 64 + b0 + r) * 320 + g * 32 + ch * 8;
            asm volatile("global_store_dwordx4 %0, %1, off sc0 sc1"
                         :: "v"(p), "v"(v) : "memory");
        }
        if (tau < S_LEN - 1) {
            const int sn = dir ? (s - 1) : (s + 1);
            const __hip_bfloat16* xp = X + (((size_t)dir * 512 + sn) * 64 + b0) * 1280 + g * 128;
#pragma unroll
            for (int r = 0; r < 4; ++r) {
                int m = (lane >> 4) * 4 + r;
                xa[r]     = xp[(size_t)m * 1280 + n0 + bb];
                xa[4 + r] = xp[(size_t)m * 1280 + n0 + 16 + bb];
            }
        }
        asm volatile("s_waitcnt vmcnt(0)" ::: "memory");
        __builtin_amdgcn_sched_barrier(0);
        __syncthreads();   // all waves' publish stores drained

        // 5) team barrier: relaxed add + relaxed spin
        cnt_target += G_SPLIT;
        if (t == 0) {
            __hip_atomic_fetch_add(myctr, 1, __ATOMIC_RELAXED, __HIP_MEMORY_SCOPE_AGENT);
            while (__hip_atomic_load(myctr, __ATOMIC_RELAXED, __HIP_MEMORY_SCOPE_AGENT) < cnt_target)
                __builtin_amdgcn_s_sleep(1);
        }
        __syncthreads();
    }
}

// ---------------------------------------------------------------------------
extern "C" void kernel_launch(void* const* d_in, const int* in_sizes, int n_in,
                              void* d_out, int out_size, void* d_ws, size_t ws_size,
                              hipStream_t stream) {
    const int*   cf    = (const int*)d_in[0];
    const int*   bl    = (const int*)d_in[1];
    const int*   br    = (const int*)d_in[2];
    const int*   scf   = (const int*)d_in[3];
    const int*   sbl   = (const int*)d_in[4];
    const int*   sbr   = (const int*)d_in[5];
    const float* ce    = (const float*)d_in[6];
    const float* be    = (const float*)d_in[7];
    const float* sce   = (const float*)d_in[8];
    const float* sbe   = (const float*)d_in[9];
    const float* Wlin  = (const float*)d_in[10];
    const float* blin  = (const float*)d_in[11];
    const float* Wih_l = (const float*)d_in[12];
    const float* Whh_l = (const float*)d_in[13];
    const float* b_l   = (const float*)d_in[14];
    const float* Wih_r = (const float*)d_in[15];
    const float* Whh_r = (const float*)d_in[16];
    const float* b_r   = (const float*)d_in[17];
    float* out = (float*)d_out;

    // Workspace layout (bytes):
    //   A bf16   [2][32768][320]     :  41,943,040
    //   X bf16   [2][512][64][1280]  : 167,772,160  (ends 209,715,200)
    //   Whh_p bf16 [2][1280][320]    :   1,638,400  (ends 211,353,600)
    //   Wih_p bf16 [2][1280][320]    :   1,638,400  (ends 212,992,000)
    //   bias_p f32 [2][1280]         :      10,240  (ends 213,002,240)
    //   hb_hi bf16 [2][2][64][320]   :     327,680  (ends 213,329,920)
    //   hb_lo bf16 [2][2][64][320]   :     327,680  (ends 213,657,600)
    //   ctr int [8]                  :          64
    char* ws = (char*)d_ws;
    __hip_bfloat16* A_b    = (__hip_bfloat16*)(ws);
    __hip_bfloat16* A_l    = A_b;
    __hip_bfloat16* A_r    = A_b + (size_t)32768 * 320;
    __hip_bfloat16* X      = (__hip_bfloat16*)(ws + 41943040);
    __hip_bfloat16* Whh_p  = (__hip_bfloat16*)(ws + 209715200);
    __hip_bfloat16* Wih_p  = (__hip_bfloat16*)(ws + 211353600);
    float*          bias_p = (float*)(ws + 212992000);
    __hip_bfloat16* hb_hi  = (__hip_bfloat16*)(ws + 213002240);
    __hip_bfloat16* hb_lo  = (__hip_bfloat16*)(ws + 213329920);
    int*            ctr    = (int*)(ws + 213657600);

    k_prep_w<<<dim3((2 * 1280 * 320 + 255) / 256), dim3(256), 0, stream>>>(
        Whh_l, Whh_r, Wih_l, Wih_r, Whh_p, Wih_p);
    k_prep_misc<<<dim3(1280), dim3(256), 0, stream>>>(b_l, b_r, hb_hi, hb_lo, bias_p, ctr);
    k_lin<<<dim3(512, 2), dim3(256), 0, stream>>>(cf, bl, br, scf, sbl, sbr,
                                                  ce, be, sce, sbe, Wlin, blin,
                                                  A_l, A_r);
    k_xgemm<<<dim3(512, 10, 2), dim3(256), 0, stream>>>(A_b, Wih_p, bias_p, X);
    k_rec<<<dim3(80), dim3(256), 0, stream>>>(X, Whh_p, hb_hi, hb_lo, ctr, out);
}

// Round 6
// 2942.824 us; speedup vs baseline: 3.6284x; 1.0683x over previous
//
#include <hip/hip_runtime.h>
#include <hip/hip_bf16.h>

// Problem constants
#define S_LEN 512
#define BATCH 64
#define DC    200
#define HID   300
#define H4    1200
#define IN_DIM 800
#define G_SPLIT 10          // gate-blocks per recurrence team (30 h-dims each)

typedef __attribute__((ext_vector_type(8))) short short8b;   // 8 bf16
typedef __attribute__((ext_vector_type(4))) float f32x4;

__device__ __forceinline__ float sigmoidf_(float x) { return 1.0f / (1.0f + __expf(-x)); }
__device__ __forceinline__ float tanhf_(float x)    { return 2.0f / (1.0f + __expf(-2.0f * x)) - 1.0f; }

// ---------------------------------------------------------------------------
// Weight prep (as R4). Gate-row permutation: block g owns rows
// [g*128, g*128+128): locals 0..119 = {i,f,g,o} x 30 h-dims, 120..127 pad.
// Whh k-PERMUTED: k-slot g2*32+jj2 <-> h-dim g2*30+jj2 (jj2>=30 zero).
// ---------------------------------------------------------------------------
__global__ void k_prep_w(const float* __restrict__ Whh_l, const float* __restrict__ Whh_r,
                         const float* __restrict__ Wih_l, const float* __restrict__ Wih_r,
                         __hip_bfloat16* __restrict__ Whh_p, __hip_bfloat16* __restrict__ Wih_p) {
    int i = blockIdx.x * 256 + threadIdx.x;        // over 2*1280*320
    if (i >= 2 * 1280 * 320) return;
    int slot = i % 320;
    int R = (i / 320) % 1280;
    int d = i / (320 * 1280);
    int g = R >> 7, local = R & 127;
    float vh = 0.f, vi = 0.f;
    if (local < 120) {
        int q = local / 30, jj = local % 30;
        int n = q * 300 + g * 30 + jj;
        const float* Whh = d ? Whh_r : Whh_l;
        const float* Wih = d ? Wih_r : Wih_l;
        int g2 = slot >> 5, jj2 = slot & 31;
        if (jj2 < 30) vh = Whh[n * 300 + g2 * 30 + jj2];
        if (slot < 300) vi = Wih[n * 300 + slot];
    }
    Whh_p[i] = __float2bfloat16(vh);
    Wih_p[i] = __float2bfloat16(vi);
}

// Zero h-buffers + tag block, build permuted bias. Runs every launch.
__global__ void k_prep_misc(const float* __restrict__ b_l, const float* __restrict__ b_r,
                            __hip_bfloat16* __restrict__ hb_hi, __hip_bfloat16* __restrict__ hb_lo,
                            float* __restrict__ bias_p, int* __restrict__ ctl) {
    int i = blockIdx.x * 256 + threadIdx.x;
    if (i < 2 * 2 * 64 * 320) {
        hb_hi[i] = __float2bfloat16(0.f);
        hb_lo[i] = __float2bfloat16(0.f);
    }
    if (i < 2 * 1280) {
        int d = i / 1280, R = i % 1280;
        int g = R >> 7, local = R & 127;
        float v = 0.f;
        if (local < 120) { int q = local / 30, jj = local % 30; v = (d ? b_r : b_l)[q * 300 + g * 30 + jj]; }
        bias_p[i] = v;
    }
    if (i < 256) ctl[i] = 0;
}

// ---------------------------------------------------------------------------
// K1: fused embedding-gather + linear + tanh, bf16 MFMA, BN=320 (unchanged R4)
// ---------------------------------------------------------------------------
__global__ __launch_bounds__(256) void k_lin(
    const int* __restrict__ cf, const int* __restrict__ bl, const int* __restrict__ br,
    const int* __restrict__ scf, const int* __restrict__ sbl, const int* __restrict__ sbr,
    const float* __restrict__ ce, const float* __restrict__ be,
    const float* __restrict__ sce, const float* __restrict__ sbe,
    const float* __restrict__ W, const float* __restrict__ bias,
    __hip_bfloat16* __restrict__ outL, __hip_bfloat16* __restrict__ outR)
{
    const int z = blockIdx.y;
    const int* dynIdx  = z ? br  : bl;
    const int* statIdx = z ? sbr : sbl;
    __hip_bfloat16* outp = z ? outR : outL;
    const int m0 = blockIdx.x * 64;

    __shared__ __align__(16) __hip_bfloat16 sA[64][40];
    __shared__ __align__(16) __hip_bfloat16 sB[320][40];
    const int t = threadIdx.x, lane = t & 63, wv = t >> 6;

    const int rA = t >> 2, c8A = (t & 3) * 8;
    const int mA = m0 + rA;
    const int idc = cf[mA], idsc = scf[mA], idd = dynIdx[mA], ids = statIdx[mA];

    f32x4 acc[4][5] = {};

    for (int k0 = 0; k0 < IN_DIM; k0 += 32) {
        {
            int k = k0 + c8A;
            int seg = k / 200, kin = k - seg * 200;
            const float* tab = (seg == 0) ? ce : (seg == 1) ? sce : (seg == 2) ? be : sbe;
            int id = (seg == 0) ? idc : (seg == 1) ? idsc : (seg == 2) ? idd : ids;
            const float* tp = tab + (size_t)id * DC + kin;
            f32x4 v0 = *reinterpret_cast<const f32x4*>(tp);
            f32x4 v1 = *reinterpret_cast<const f32x4*>(tp + 4);
            union { short8b v; __hip_bfloat16 h[8]; } u;
#pragma unroll
            for (int q = 0; q < 4; ++q) { u.h[q] = __float2bfloat16(v0[q]); u.h[4 + q] = __float2bfloat16(v1[q]); }
            *reinterpret_cast<short8b*>(&sA[rA][c8A]) = u.v;
        }
#pragma unroll
        for (int j = 0; j < 5; ++j) {
            int i = t + j * 256;
            int n = i >> 2, ch = (i & 3) * 8;
            f32x4 v0 = {0, 0, 0, 0}, v1 = {0, 0, 0, 0};
            if (n < HID) {
                const float* wp = W + (size_t)n * IN_DIM + k0 + ch;
                v0 = *reinterpret_cast<const f32x4*>(wp);
                v1 = *reinterpret_cast<const f32x4*>(wp + 4);
            }
            union { short8b v; __hip_bfloat16 h[8]; } u;
#pragma unroll
            for (int q = 0; q < 4; ++q) { u.h[q] = __float2bfloat16(v0[q]); u.h[4 + q] = __float2bfloat16(v1[q]); }
            *reinterpret_cast<short8b*>(&sB[n][ch]) = u.v;
        }
        __syncthreads();
        const int kl = (lane >> 4) * 8, bb = lane & 15;
#pragma unroll
        for (int mt = 0; mt < 4; ++mt) {
            short8b af = *reinterpret_cast<const short8b*>(&sA[mt * 16 + bb][kl]);
#pragma unroll
            for (int nt = 0; nt < 5; ++nt) {
                short8b bf = *reinterpret_cast<const short8b*>(&sB[(wv * 5 + nt) * 16 + bb][kl]);
                acc[mt][nt] = __builtin_amdgcn_mfma_f32_16x16x32_bf16(af, bf, acc[mt][nt], 0, 0, 0);
            }
        }
        __syncthreads();
    }
    const int bb = lane & 15;
#pragma unroll
    for (int mt = 0; mt < 4; ++mt)
#pragma unroll
        for (int nt = 0; nt < 5; ++nt) {
            int p = (wv * 5 + nt) * 16 + bb;
            float bv = (p < HID) ? bias[p] : 0.f;
#pragma unroll
            for (int r = 0; r < 4; ++r) {
                int m = m0 + mt * 16 + (lane >> 4) * 4 + r;
                float val = (p < HID) ? tanhf_(acc[mt][nt][r] + bv) : 0.f;
                outp[(size_t)m * 320 + p] = __float2bfloat16(val);
            }
        }
}

// ---------------------------------------------------------------------------
// K2: X = A @ Wih_p^T + bias_p, bf16 MFMA 16x16x32 (unchanged R4)
// ---------------------------------------------------------------------------
__global__ __launch_bounds__(256) void k_xgemm(
    const __hip_bfloat16* __restrict__ A,
    const __hip_bfloat16* __restrict__ Wih_p,
    const float* __restrict__ bias_p,
    __hip_bfloat16* __restrict__ Xout)
{
    const int dir = blockIdx.z;
    const int m0 = blockIdx.x * 64;
    const int n0 = blockIdx.y * 128;
    const __hip_bfloat16* Ad = A + (size_t)dir * 32768 * 320;
    const __hip_bfloat16* Wd = Wih_p + (size_t)dir * 1280 * 320;
    const float* bd = bias_p + dir * 1280;
    __hip_bfloat16* Xd = Xout + (size_t)dir * 512 * 64 * 1280;

    __shared__ __align__(16) __hip_bfloat16 sA[64][40];
    __shared__ __align__(16) __hip_bfloat16 sB[128][40];
    const int t = threadIdx.x, lane = t & 63, wv = t >> 6;
    f32x4 acc[4][2] = {};

    for (int k0 = 0; k0 < 320; k0 += 32) {
        {
            int r = t >> 2, kg = (t & 3) * 8;
            *reinterpret_cast<short8b*>(&sA[r][kg]) =
                *reinterpret_cast<const short8b*>(Ad + (size_t)(m0 + r) * 320 + k0 + kg);
        }
#pragma unroll
        for (int i = 0; i < 2; ++i) {
            int c = t + i * 256;
            int r = c >> 2, kg = (c & 3) * 8;
            *reinterpret_cast<short8b*>(&sB[r][kg]) =
                *reinterpret_cast<const short8b*>(Wd + (size_t)(n0 + r) * 320 + k0 + kg);
        }
        __syncthreads();
        const int kl = (lane >> 4) * 8;
#pragma unroll
        for (int mt = 0; mt < 4; ++mt) {
            short8b af = *reinterpret_cast<const short8b*>(&sA[mt * 16 + (lane & 15)][kl]);
#pragma unroll
            for (int nt = 0; nt < 2; ++nt) {
                short8b bf = *reinterpret_cast<const short8b*>(&sB[(wv * 2 + nt) * 16 + (lane & 15)][kl]);
                acc[mt][nt] = __builtin_amdgcn_mfma_f32_16x16x32_bf16(af, bf, acc[mt][nt], 0, 0, 0);
            }
        }
        __syncthreads();
    }
#pragma unroll
    for (int mt = 0; mt < 4; ++mt)
#pragma unroll
        for (int nt = 0; nt < 2; ++nt) {
            int p = n0 + (wv * 2 + nt) * 16 + (lane & 15);
            float bv = bd[p];
#pragma unroll
            for (int r = 0; r < 4; ++r) {
                int m = m0 + mt * 16 + (lane >> 4) * 4 + r;
                int b = m >> 9, s = m & 511;
                Xd[(size_t)(s * 64 + b) * 1280 + p] = __float2bfloat16(acc[mt][nt][r] + bv);
            }
        }
}

// ---------------------------------------------------------------------------
// K3: LSTM recurrence — weight-stationary teams, tag-based device-scope sync.
// 80 blocks = 2 dirs x 4 batch-groups(16) x 10 gate-blocks. Fixed teams by
// blockIdx (no placement games). Whh B-fragments live in REGISTERS (80 VGPR).
// Per step: all-wave tag poll -> h direct to MFMA A-frags (sc0 sc1) -> MFMA
// -> nonlin -> wave0 publishes h + tag; waves1-3 write out. 2 barriers/step.
// ---------------------------------------------------------------------------
__global__ __launch_bounds__(256) void k_rec(
    const __hip_bfloat16* __restrict__ X,      // [2][512][64][1280]
    const __hip_bfloat16* __restrict__ Whh_p,  // [2][1280][320] (k-permuted)
    __hip_bfloat16* __restrict__ hb_hi,        // [2][2][64][320]
    __hip_bfloat16* __restrict__ hb_lo,
    int* __restrict__ ctl,                     // [256]: team t tags at ctl[t*16+g]
    float* __restrict__ out)                   // [64][512][600]
{
    const int bid = blockIdx.x;
    const int dir = bid / (4 * G_SPLIT);
    const int grp = (bid / G_SPLIT) % 4;
    const int g   = bid % G_SPLIT;
    const int t = threadIdx.x;
    const int lane = t & 63, wv = t >> 6;
    const int b0 = grp * 16;

    __shared__ float sG[16][132];              // +4 pad: kills 4-way store conflicts
    __shared__ float sC[16][32];
    __shared__ __align__(16) __hip_bfloat16 sPub[2][16][32];

    const int n0 = wv * 32;
    const int bb = lane & 15;
    const int hi4 = lane >> 4;

    // Whh B-fragments -> registers (step-invariant; 20 x short8b = 80 VGPRs)
    short8b wB0[10], wB1[10];
    {
        const __hip_bfloat16* Wsrc = Whh_p + ((size_t)dir * 1280 + g * 128) * 320;
#pragma unroll
        for (int kt = 0; kt < 10; ++kt) {
            wB0[kt] = *reinterpret_cast<const short8b*>(Wsrc + (size_t)(n0 + bb) * 320 + kt * 32 + hi4 * 8);
            wB1[kt] = *reinterpret_cast<const short8b*>(Wsrc + (size_t)(n0 + 16 + bb) * 320 + kt * 32 + hi4 * 8);
        }
    }
    for (int i = t; i < 16 * 32; i += 256) sC[i >> 5][i & 31] = 0.f;
    __syncthreads();

    int* tags = ctl + (dir * 4 + grp) * 16;
    const int mylane = (lane < G_SPLIT) ? lane : 0;

    // X prefetch registers (8 bf16 per thread)
    __hip_bfloat16 xa[8];
    {
        const int s0 = dir ? (S_LEN - 1) : 0;
        const __hip_bfloat16* xp = X + (((size_t)dir * 512 + s0) * 64 + b0) * 1280 + g * 128;
#pragma unroll
        for (int r = 0; r < 4; ++r) {
            int m = hi4 * 4 + r;
            xa[r]     = xp[(size_t)m * 1280 + n0 + bb];
            xa[4 + r] = xp[(size_t)m * 1280 + n0 + 16 + bb];
        }
    }

    for (int tau = 0; tau < S_LEN; ++tau) {
        const int s = dir ? (S_LEN - 1 - tau) : tau;
        const int par = tau & 1;

        // 1) all-wave parallel tag poll: teammates published h(tau)?
        if (tau > 0) {
            int tg;
            do {
                __builtin_amdgcn_s_sleep(1);
                tg = __hip_atomic_load(tags + mylane, __ATOMIC_RELAXED, __HIP_MEMORY_SCOPE_AGENT);
            } while (!__all(tg >= tau));
        }

        // 2) h -> MFMA A-fragments, direct to registers (device-coherent loads)
        short8b ahi[10], alo[10];
        const char* hpi = (const char*)(hb_hi + (((size_t)dir * 2 + par) * 64 + b0 + bb) * 320 + hi4 * 8);
        const char* hpl = (const char*)(hb_lo + (((size_t)dir * 2 + par) * 64 + b0 + bb) * 320 + hi4 * 8);
#pragma unroll
        for (int kt = 0; kt < 10; ++kt) {
            asm volatile("global_load_dwordx4 %0, %1, off sc0 sc1" : "=v"(ahi[kt]) : "v"(hpi + kt * 64));
            asm volatile("global_load_dwordx4 %0, %1, off sc0 sc1" : "=v"(alo[kt]) : "v"(hpl + kt * 64));
        }
        asm volatile("s_waitcnt vmcnt(0)" ::: "memory");
        __builtin_amdgcn_sched_barrier(0);

        // 3) gates = X + h_hi @ W + h_lo @ W  (B-operands from registers)
        f32x4 acc0, acc1;
#pragma unroll
        for (int r = 0; r < 4; ++r) {
            acc0[r] = __bfloat162float(xa[r]);
            acc1[r] = __bfloat162float(xa[4 + r]);
        }
#pragma unroll
        for (int kt = 0; kt < 10; ++kt) {
            acc0 = __builtin_amdgcn_mfma_f32_16x16x32_bf16(ahi[kt], wB0[kt], acc0, 0, 0, 0);
            acc1 = __builtin_amdgcn_mfma_f32_16x16x32_bf16(ahi[kt], wB1[kt], acc1, 0, 0, 0);
            acc0 = __builtin_amdgcn_mfma_f32_16x16x32_bf16(alo[kt], wB0[kt], acc0, 0, 0, 0);
            acc1 = __builtin_amdgcn_mfma_f32_16x16x32_bf16(alo[kt], wB1[kt], acc1, 0, 0, 0);
        }
#pragma unroll
        for (int r = 0; r < 4; ++r) {
            int m = hi4 * 4 + r;
            sG[m][n0 + bb] = acc0[r];
            sG[m][n0 + 16 + bb] = acc1[r];
        }
        __syncthreads();   // B: gates visible

        // 4) nonlinearity + cell update -> sPub (hi/lo), pads zeroed
#pragma unroll
        for (int w = t; w < 512; w += 256) {
            int b = w >> 5, jj = w & 31;
            __hip_bfloat16 hhi_ = __float2bfloat16(0.f), hlo_ = __float2bfloat16(0.f);
            if (jj < 30) {
                float ig = sigmoidf_(sG[b][jj]);
                float fg = sigmoidf_(sG[b][30 + jj]);
                float gg = tanhf_(sG[b][60 + jj]);
                float og = sigmoidf_(sG[b][90 + jj]);
                float cn = fg * sC[b][jj] + ig * gg;
                sC[b][jj] = cn;
                float hvv = og * tanhf_(cn);
                hhi_ = __float2bfloat16(hvv);
                hlo_ = __float2bfloat16(hvv - __bfloat162float(hhi_));
            }
            sPub[0][b][jj] = hhi_;
            sPub[1][b][jj] = hlo_;
        }
        __syncthreads();   // C: sPub ready

        // 5) wave0: publish h (2KB) -> ack -> tag.  waves1-3: out stores.
        if (wv == 0) {
#pragma unroll
            for (int i = 0; i < 2; ++i) {
                int c = lane + 64 * i;              // 0..127 chunks (hi then lo)
                int r = (c >> 2) & 15, ch = c & 3;
                f32x4 v = *reinterpret_cast<f32x4*>(&sPub[i][r][ch * 8]);
                __hip_bfloat16* p = (i ? hb_lo : hb_hi)
                    + (((size_t)dir * 2 + (par ^ 1)) * 64 + b0 + r) * 320 + g * 32 + ch * 8;
                asm volatile("global_store_dwordx4 %0, %1, off sc0 sc1" :: "v"(p), "v"(v) : "memory");
            }
            asm volatile("s_waitcnt vmcnt(0)" ::: "memory");
            if (t == 0)
                __hip_atomic_store(tags + g, tau + 1, __ATOMIC_RELAXED, __HIP_MEMORY_SCOPE_AGENT);
        } else {
            for (int w = t - 64; w < 480; w += 192) {
                int b = w / 30, jj = w - b * 30;
                float v = __bfloat162float(sPub[0][b][jj]) + __bfloat162float(sPub[1][b][jj]);
                out[((size_t)(b0 + b) * S_LEN + s) * 600 + dir * 300 + g * 30 + jj] = v;
            }
        }

        // 6) X(t+1) prefetch (overlaps teammates' publish latency)
        if (tau < S_LEN - 1) {
            const int sn = dir ? (s - 1) : (s + 1);
            const __hip_bfloat16* xp = X + (((size_t)dir * 512 + sn) * 64 + b0) * 1280 + g * 128;
#pragma unroll
            for (int r = 0; r < 4; ++r) {
                int m = hi4 * 4 + r;
                xa[r]     = xp[(size_t)m * 1280 + n0 + bb];
                xa[4 + r] = xp[(size_t)m * 1280 + n0 + 16 + bb];
            }
        }
        // no barrier: next iteration's poll is the synchronization
    }
}

// ---------------------------------------------------------------------------
extern "C" void kernel_launch(void* const* d_in, const int* in_sizes, int n_in,
                              void* d_out, int out_size, void* d_ws, size_t ws_size,
                              hipStream_t stream) {
    const int*   cf    = (const int*)d_in[0];
    const int*   bl    = (const int*)d_in[1];
    const int*   br    = (const int*)d_in[2];
    const int*   scf   = (const int*)d_in[3];
    const int*   sbl   = (const int*)d_in[4];
    const int*   sbr   = (const int*)d_in[5];
    const float* ce    = (const float*)d_in[6];
    const float* be    = (const float*)d_in[7];
    const float* sce   = (const float*)d_in[8];
    const float* sbe   = (const float*)d_in[9];
    const float* Wlin  = (const float*)d_in[10];
    const float* blin  = (const float*)d_in[11];
    const float* Wih_l = (const float*)d_in[12];
    const float* Whh_l = (const float*)d_in[13];
    const float* b_l   = (const float*)d_in[14];
    const float* Wih_r = (const float*)d_in[15];
    const float* Whh_r = (const float*)d_in[16];
    const float* b_r   = (const float*)d_in[17];
    float* out = (float*)d_out;

    // Workspace layout (bytes):
    //   A bf16   [2][32768][320]     :  41,943,040
    //   X bf16   [2][512][64][1280]  : 167,772,160  (ends 209,715,200)
    //   Whh_p bf16 [2][1280][320]    :   1,638,400  (ends 211,353,600)
    //   Wih_p bf16 [2][1280][320]    :   1,638,400  (ends 212,992,000)
    //   bias_p f32 [2][1280]         :      10,240  (ends 213,002,240)
    //   hb_hi bf16 [2][2][64][320]   :     327,680  (ends 213,329,920)
    //   hb_lo bf16 [2][2][64][320]   :     327,680  (ends 213,657,600)
    //   ctl int [256]                :       1,024
    char* ws = (char*)d_ws;
    __hip_bfloat16* A_b    = (__hip_bfloat16*)(ws);
    __hip_bfloat16* A_l    = A_b;
    __hip_bfloat16* A_r    = A_b + (size_t)32768 * 320;
    __hip_bfloat16* X      = (__hip_bfloat16*)(ws + 41943040);
    __hip_bfloat16* Whh_p  = (__hip_bfloat16*)(ws + 209715200);
    __hip_bfloat16* Wih_p  = (__hip_bfloat16*)(ws + 211353600);
    float*          bias_p = (float*)(ws + 212992000);
    __hip_bfloat16* hb_hi  = (__hip_bfloat16*)(ws + 213002240);
    __hip_bfloat16* hb_lo  = (__hip_bfloat16*)(ws + 213329920);
    int*            ctl    = (int*)(ws + 213657600);

    k_prep_w<<<dim3((2 * 1280 * 320 + 255) / 256), dim3(256), 0, stream>>>(
        Whh_l, Whh_r, Wih_l, Wih_r, Whh_p, Wih_p);
    k_prep_misc<<<dim3(1280), dim3(256), 0, stream>>>(b_l, b_r, hb_hi, hb_lo, bias_p, ctl);
    k_lin<<<dim3(512, 2), dim3(256), 0, stream>>>(cf, bl, br, scf, sbl, sbr,
                                                  ce, be, sce, sbe, Wlin, blin,
                                                  A_l, A_r);
    k_xgemm<<<dim3(512, 10, 2), dim3(256), 0, stream>>>(A_b, Wih_p, bias_p, X);
    k_rec<<<dim3(80), dim3(256), 0, stream>>>(X, Whh_p, hb_hi, hb_lo, ctl, out);
}

// Round 7
// 2288.563 us; speedup vs baseline: 4.6657x; 1.2859x over previous
//
#include <hip/hip_runtime.h>
#include <hip/hip_bf16.h>

// Problem constants
#define S_LEN 512
#define BATCH 64
#define DC    200
#define HID   300
#define H4    1200
#define IN_DIM 800
#define G_SPLIT 10          // gate-blocks per recurrence team (30 h-dims each)

typedef __attribute__((ext_vector_type(8))) short short8b;   // 8 bf16
typedef __attribute__((ext_vector_type(4))) float f32x4;
typedef __attribute__((ext_vector_type(4))) int   i32x4;

__device__ __forceinline__ float sigmoidf_(float x) { return 1.0f / (1.0f + __expf(-x)); }
__device__ __forceinline__ float tanhf_(float x)    { return 2.0f / (1.0f + __expf(-2.0f * x)) - 1.0f; }

// ---------------------------------------------------------------------------
// Weight prep (as R4/R6). Gate-row permutation: block g owns rows
// [g*128, g*128+128): locals 0..119 = {i,f,g,o} x 30 h-dims, 120..127 pad.
// Whh k-PERMUTED: k-slot g2*32+jj2 <-> h-dim g2*30+jj2 (jj2>=30 zero).
// ---------------------------------------------------------------------------
__global__ void k_prep_w(const float* __restrict__ Whh_l, const float* __restrict__ Whh_r,
                         const float* __restrict__ Wih_l, const float* __restrict__ Wih_r,
                         __hip_bfloat16* __restrict__ Whh_p, __hip_bfloat16* __restrict__ Wih_p) {
    int i = blockIdx.x * 256 + threadIdx.x;        // over 2*1280*320
    if (i >= 2 * 1280 * 320) return;
    int slot = i % 320;
    int R = (i / 320) % 1280;
    int d = i / (320 * 1280);
    int g = R >> 7, local = R & 127;
    float vh = 0.f, vi = 0.f;
    if (local < 120) {
        int q = local / 30, jj = local % 30;
        int n = q * 300 + g * 30 + jj;
        const float* Whh = d ? Whh_r : Whh_l;
        const float* Wih = d ? Wih_r : Wih_l;
        int g2 = slot >> 5, jj2 = slot & 31;
        if (jj2 < 30) vh = Whh[n * 300 + g2 * 30 + jj2];
        if (slot < 300) vi = Wih[n * 300 + slot];
    }
    Whh_p[i] = __float2bfloat16(vh);
    Wih_p[i] = __float2bfloat16(vi);
}

// Zero stamped h-buffer, build permuted bias. Runs every launch (graph replay).
__global__ void k_prep_misc(const float* __restrict__ b_l, const float* __restrict__ b_r,
                            int* __restrict__ hb_st,        // [2][2][64][100] i32x4 = 102400 ints
                            float* __restrict__ bias_p) {
    int i = blockIdx.x * 256 + threadIdx.x;
    if (i < 102400) hb_st[i] = 0;
    if (i < 2 * 1280) {
        int d = i / 1280, R = i % 1280;
        int g = R >> 7, local = R & 127;
        float v = 0.f;
        if (local < 120) { int q = local / 30, jj = local % 30; v = (d ? b_r : b_l)[q * 300 + g * 30 + jj]; }
        bias_p[i] = v;
    }
}

// ---------------------------------------------------------------------------
// K1: fused embedding-gather + linear + tanh, bf16 MFMA, BN=320 (unchanged R4)
// ---------------------------------------------------------------------------
__global__ __launch_bounds__(256) void k_lin(
    const int* __restrict__ cf, const int* __restrict__ bl, const int* __restrict__ br,
    const int* __restrict__ scf, const int* __restrict__ sbl, const int* __restrict__ sbr,
    const float* __restrict__ ce, const float* __restrict__ be,
    const float* __restrict__ sce, const float* __restrict__ sbe,
    const float* __restrict__ W, const float* __restrict__ bias,
    __hip_bfloat16* __restrict__ outL, __hip_bfloat16* __restrict__ outR)
{
    const int z = blockIdx.y;
    const int* dynIdx  = z ? br  : bl;
    const int* statIdx = z ? sbr : sbl;
    __hip_bfloat16* outp = z ? outR : outL;
    const int m0 = blockIdx.x * 64;

    __shared__ __align__(16) __hip_bfloat16 sA[64][40];
    __shared__ __align__(16) __hip_bfloat16 sB[320][40];
    const int t = threadIdx.x, lane = t & 63, wv = t >> 6;

    const int rA = t >> 2, c8A = (t & 3) * 8;
    const int mA = m0 + rA;
    const int idc = cf[mA], idsc = scf[mA], idd = dynIdx[mA], ids = statIdx[mA];

    f32x4 acc[4][5] = {};

    for (int k0 = 0; k0 < IN_DIM; k0 += 32) {
        {
            int k = k0 + c8A;
            int seg = k / 200, kin = k - seg * 200;
            const float* tab = (seg == 0) ? ce : (seg == 1) ? sce : (seg == 2) ? be : sbe;
            int id = (seg == 0) ? idc : (seg == 1) ? idsc : (seg == 2) ? idd : ids;
            const float* tp = tab + (size_t)id * DC + kin;
            f32x4 v0 = *reinterpret_cast<const f32x4*>(tp);
            f32x4 v1 = *reinterpret_cast<const f32x4*>(tp + 4);
            union { short8b v; __hip_bfloat16 h[8]; } u;
#pragma unroll
            for (int q = 0; q < 4; ++q) { u.h[q] = __float2bfloat16(v0[q]); u.h[4 + q] = __float2bfloat16(v1[q]); }
            *reinterpret_cast<short8b*>(&sA[rA][c8A]) = u.v;
        }
#pragma unroll
        for (int j = 0; j < 5; ++j) {
            int i = t + j * 256;
            int n = i >> 2, ch = (i & 3) * 8;
            f32x4 v0 = {0, 0, 0, 0}, v1 = {0, 0, 0, 0};
            if (n < HID) {
                const float* wp = W + (size_t)n * IN_DIM + k0 + ch;
                v0 = *reinterpret_cast<const f32x4*>(wp);
                v1 = *reinterpret_cast<const f32x4*>(wp + 4);
            }
            union { short8b v; __hip_bfloat16 h[8]; } u;
#pragma unroll
            for (int q = 0; q < 4; ++q) { u.h[q] = __float2bfloat16(v0[q]); u.h[4 + q] = __float2bfloat16(v1[q]); }
            *reinterpret_cast<short8b*>(&sB[n][ch]) = u.v;
        }
        __syncthreads();
        const int kl = (lane >> 4) * 8, bb = lane & 15;
#pragma unroll
        for (int mt = 0; mt < 4; ++mt) {
            short8b af = *reinterpret_cast<const short8b*>(&sA[mt * 16 + bb][kl]);
#pragma unroll
            for (int nt = 0; nt < 5; ++nt) {
                short8b bf = *reinterpret_cast<const short8b*>(&sB[(wv * 5 + nt) * 16 + bb][kl]);
                acc[mt][nt] = __builtin_amdgcn_mfma_f32_16x16x32_bf16(af, bf, acc[mt][nt], 0, 0, 0);
            }
        }
        __syncthreads();
    }
    const int bb = lane & 15;
#pragma unroll
    for (int mt = 0; mt < 4; ++mt)
#pragma unroll
        for (int nt = 0; nt < 5; ++nt) {
            int p = (wv * 5 + nt) * 16 + bb;
            float bv = (p < HID) ? bias[p] : 0.f;
#pragma unroll
            for (int r = 0; r < 4; ++r) {
                int m = m0 + mt * 16 + (lane >> 4) * 4 + r;
                float val = (p < HID) ? tanhf_(acc[mt][nt][r] + bv) : 0.f;
                outp[(size_t)m * 320 + p] = __float2bfloat16(val);
            }
        }
}

// ---------------------------------------------------------------------------
// K2: X = A @ Wih_p^T + bias_p, bf16 MFMA 16x16x32 (unchanged R4)
// ---------------------------------------------------------------------------
__global__ __launch_bounds__(256) void k_xgemm(
    const __hip_bfloat16* __restrict__ A,
    const __hip_bfloat16* __restrict__ Wih_p,
    const float* __restrict__ bias_p,
    __hip_bfloat16* __restrict__ Xout)
{
    const int dir = blockIdx.z;
    const int m0 = blockIdx.x * 64;
    const int n0 = blockIdx.y * 128;
    const __hip_bfloat16* Ad = A + (size_t)dir * 32768 * 320;
    const __hip_bfloat16* Wd = Wih_p + (size_t)dir * 1280 * 320;
    const float* bd = bias_p + dir * 1280;
    __hip_bfloat16* Xd = Xout + (size_t)dir * 512 * 64 * 1280;

    __shared__ __align__(16) __hip_bfloat16 sA[64][40];
    __shared__ __align__(16) __hip_bfloat16 sB[128][40];
    const int t = threadIdx.x, lane = t & 63, wv = t >> 6;
    f32x4 acc[4][2] = {};

    for (int k0 = 0; k0 < 320; k0 += 32) {
        {
            int r = t >> 2, kg = (t & 3) * 8;
            *reinterpret_cast<short8b*>(&sA[r][kg]) =
                *reinterpret_cast<const short8b*>(Ad + (size_t)(m0 + r) * 320 + k0 + kg);
        }
#pragma unroll
        for (int i = 0; i < 2; ++i) {
            int c = t + i * 256;
            int r = c >> 2, kg = (c & 3) * 8;
            *reinterpret_cast<short8b*>(&sB[r][kg]) =
                *reinterpret_cast<const short8b*>(Wd + (size_t)(n0 + r) * 320 + k0 + kg);
        }
        __syncthreads();
        const int kl = (lane >> 4) * 8;
#pragma unroll
        for (int mt = 0; mt < 4; ++mt) {
            short8b af = *reinterpret_cast<const short8b*>(&sA[mt * 16 + (lane & 15)][kl]);
#pragma unroll
            for (int nt = 0; nt < 2; ++nt) {
                short8b bf = *reinterpret_cast<const short8b*>(&sB[(wv * 2 + nt) * 16 + (lane & 15)][kl]);
                acc[mt][nt] = __builtin_amdgcn_mfma_f32_16x16x32_bf16(af, bf, acc[mt][nt], 0, 0, 0);
            }
        }
        __syncthreads();
    }
#pragma unroll
    for (int mt = 0; mt < 4; ++mt)
#pragma unroll
        for (int nt = 0; nt < 2; ++nt) {
            int p = n0 + (wv * 2 + nt) * 16 + (lane & 15);
            float bv = bd[p];
#pragma unroll
            for (int r = 0; r < 4; ++r) {
                int m = m0 + mt * 16 + (lane >> 4) * 4 + r;
                int b = m >> 9, s = m & 511;
                Xd[(size_t)(s * 64 + b) * 1280 + p] = __float2bfloat16(acc[mt][nt][r] + bv);
            }
        }
}

// ---------------------------------------------------------------------------
// K3: LSTM recurrence — seqlock-stamped h exchange (no tags, no drain legs).
// 80 blocks = 2 dirs x 4 batch-groups(16) x 10 gate-blocks.
// h chunk = 16B [stamp=tau+1 | 6 bf16], one dwordx4 sc0sc1 store (16B atomic).
// Consumer: poll-load its 1600 chunks (7/thread, one vmcnt) until all stamps
// == tau — readiness + data in ONE round trip. Stage payload -> LDS -> MFMA.
// Producer: 80 threads compute 6 h-dims each (cell state in registers),
// pack + store 2 stamped chunks, write out. 2 barriers/step.
// ---------------------------------------------------------------------------
__global__ __launch_bounds__(256) void k_rec(
    const __hip_bfloat16* __restrict__ X,      // [2][512][64][1280]
    const __hip_bfloat16* __restrict__ Whh_p,  // [2][1280][320] (k-permuted)
    i32x4* __restrict__ hb_st,                 // [2][2][64][100] stamped chunks
    float* __restrict__ out)                   // [64][512][600]
{
    const int bid = blockIdx.x;
    const int dir = bid / (4 * G_SPLIT);
    const int grp = (bid / G_SPLIT) % 4;
    const int g   = bid % G_SPLIT;
    const int t = threadIdx.x;
    const int lane = t & 63, wv = t >> 6;
    const int b0 = grp * 16;

    __shared__ __align__(16) __hip_bfloat16 sHi[16][328];   // stride 656B: 2-way max on frag reads
    __shared__ __align__(16) __hip_bfloat16 sLo[16][328];
    __shared__ float sG[16][132];
    unsigned* sHiW = (unsigned*)sHi;
    unsigned* sLoW = (unsigned*)sLo;

    const int n0 = wv * 32;
    const int bb = lane & 15;
    const int hi4 = lane >> 4;

    // Whh B-fragments -> registers (step-invariant; 20 x short8b = 80 VGPRs)
    short8b wB0[10], wB1[10];
    {
        const __hip_bfloat16* Wsrc = Whh_p + ((size_t)dir * 1280 + g * 128) * 320;
#pragma unroll
        for (int kt = 0; kt < 10; ++kt) {
            wB0[kt] = *reinterpret_cast<const short8b*>(Wsrc + (size_t)(n0 + bb) * 320 + kt * 32 + hi4 * 8);
            wB1[kt] = *reinterpret_cast<const short8b*>(Wsrc + (size_t)(n0 + 16 + bb) * 320 + kt * 32 + hi4 * 8);
        }
    }
    // prezero LDS h arrays (pad slots jj>=30 stay zero forever)
    for (int i = t; i < 16 * 164; i += 256) { sHiW[i] = 0; sLoW[i] = 0; }
    __syncthreads();

    float cst[6] = {};                       // producer cell state (threads 0..79)

    // X prefetch registers (8 bf16 per thread)
    __hip_bfloat16 xa[8];
    {
        const int s0 = dir ? (S_LEN - 1) : 0;
        const __hip_bfloat16* xp = X + (((size_t)dir * 512 + s0) * 64 + b0) * 1280 + g * 128;
#pragma unroll
        for (int r = 0; r < 4; ++r) {
            int m = hi4 * 4 + r;
            xa[r]     = xp[(size_t)m * 1280 + n0 + bb];
            xa[4 + r] = xp[(size_t)m * 1280 + n0 + 16 + bb];
        }
    }

    for (int tau = 0; tau < S_LEN; ++tau) {
        const int s = dir ? (S_LEN - 1 - tau) : tau;
        const int par = tau & 1;

        // 1) poll-load stamped chunks: ready when every stamp == tau
        i32x4 ch[7];
        const i32x4* hbase = hb_st + ((size_t)(dir * 2 + par) * 64 + b0) * 100;
        for (;;) {
            bool ok = true;
#pragma unroll
            for (int k = 0; k < 7; ++k) {
                int idx = t + k * 256;
                if (idx < 1600)
                    asm volatile("global_load_dwordx4 %0, %1, off sc0 sc1"
                                 : "=v"(ch[k]) : "v"(hbase + idx) : "memory");
            }
            asm volatile("s_waitcnt vmcnt(0)" ::: "memory");
#pragma unroll
            for (int k = 0; k < 7; ++k) {
                int idx = t + k * 256;
                if (idx < 1600 && ch[k][0] != tau) ok = false;
            }
            if (ok) break;
            __builtin_amdgcn_s_sleep(1);
        }
        __builtin_amdgcn_sched_barrier(0);

        // 2) stage payloads -> LDS (strip stamps)
#pragma unroll
        for (int k = 0; k < 7; ++k) {
            int idx = t + k * 256;
            if (idx < 1600) {
                int b = idx / 100, rem = idx - b * 100;
                int g2 = rem / 10, c = rem - g2 * 10;
                int chi = (c < 5) ? c : c - 5;
                unsigned* dst = ((c < 5) ? sHiW : sLoW) + b * 164 + g2 * 16 + chi * 3;
                dst[0] = (unsigned)ch[k][1];
                dst[1] = (unsigned)ch[k][2];
                dst[2] = (unsigned)ch[k][3];
            }
        }
        __syncthreads();                    // staging complete (also fences vs prev MFMA reads)

        // 3) gates = X + h_hi @ W + h_lo @ W
        f32x4 acc0, acc1;
#pragma unroll
        for (int r = 0; r < 4; ++r) {
            acc0[r] = __bfloat162float(xa[r]);
            acc1[r] = __bfloat162float(xa[4 + r]);
        }
#pragma unroll
        for (int kt = 0; kt < 10; ++kt) {
            short8b ahi = *reinterpret_cast<const short8b*>(&sHi[bb][kt * 32 + hi4 * 8]);
            short8b alo = *reinterpret_cast<const short8b*>(&sLo[bb][kt * 32 + hi4 * 8]);
            acc0 = __builtin_amdgcn_mfma_f32_16x16x32_bf16(ahi, wB0[kt], acc0, 0, 0, 0);
            acc1 = __builtin_amdgcn_mfma_f32_16x16x32_bf16(ahi, wB1[kt], acc1, 0, 0, 0);
            acc0 = __builtin_amdgcn_mfma_f32_16x16x32_bf16(alo, wB0[kt], acc0, 0, 0, 0);
            acc1 = __builtin_amdgcn_mfma_f32_16x16x32_bf16(alo, wB1[kt], acc1, 0, 0, 0);
        }
#pragma unroll
        for (int r = 0; r < 4; ++r) {
            int m = hi4 * 4 + r;
            sG[m][n0 + bb] = acc0[r];
            sG[m][n0 + 16 + bb] = acc1[r];
        }
        __syncthreads();                    // gates visible; all frag reads of sHi/sLo done

        // 4) producer threads (t<80): nonlin on 6 h-dims, cell in regs,
        //    pack stamped chunks, publish, write out.
        if (t < 80) {
            int b = t / 5, c5 = t - (b * 5), jj0 = c5 * 6;
            float hv[6];
            unsigned hius[6], lous[6];
#pragma unroll
            for (int u = 0; u < 6; ++u) {
                int jj = jj0 + u;
                float ig = sigmoidf_(sG[b][jj]);
                float fg = sigmoidf_(sG[b][30 + jj]);
                float gg = tanhf_(sG[b][60 + jj]);
                float og = sigmoidf_(sG[b][90 + jj]);
                float cn = fg * cst[u] + ig * gg;
                cst[u] = cn;
                float h = og * tanhf_(cn);
                hv[u] = h;
                __hip_bfloat16 hb_ = __float2bfloat16(h);
                float lof = h - __bfloat162float(hb_);
                __hip_bfloat16 lb_ = __float2bfloat16(lof);
                union { __hip_bfloat16 x; unsigned short u16; } ch1{hb_}, ch2{lb_};
                hius[u] = ch1.u16;
                lous[u] = ch2.u16;
            }
            i32x4 dhi, dlo;
            dhi[0] = tau + 1; dhi[1] = (int)(hius[0] | (hius[1] << 16));
            dhi[2] = (int)(hius[2] | (hius[3] << 16)); dhi[3] = (int)(hius[4] | (hius[5] << 16));
            dlo[0] = tau + 1; dlo[1] = (int)(lous[0] | (lous[1] << 16));
            dlo[2] = (int)(lous[2] | (lous[3] << 16)); dlo[3] = (int)(lous[4] | (lous[5] << 16));
            i32x4* pb = hb_st + ((size_t)(dir * 2 + (par ^ 1)) * 64 + b0 + b) * 100 + g * 10 + c5;
            // guard against same-address store reorder with publish from 2 steps ago
            asm volatile("s_waitcnt vmcnt(0)" ::: "memory");
            asm volatile("global_store_dwordx4 %0, %1, off sc0 sc1" :: "v"(pb), "v"(dhi) : "memory");
            asm volatile("global_store_dwordx4 %0, %1, off sc0 sc1" :: "v"(pb + 5), "v"(dlo) : "memory");
            float* op = out + ((size_t)(b0 + b) * S_LEN + s) * 600 + dir * 300 + g * 30 + jj0;
#pragma unroll
            for (int u = 0; u < 6; ++u) op[u] = hv[u];
        }

        // 5) X(t+1) prefetch (overlaps teammates' publish transit)
        if (tau < S_LEN - 1) {
            const int sn = dir ? (s - 1) : (s + 1);
            const __hip_bfloat16* xp = X + (((size_t)dir * 512 + sn) * 64 + b0) * 1280 + g * 128;
#pragma unroll
            for (int r = 0; r < 4; ++r) {
                int m = hi4 * 4 + r;
                xa[r]     = xp[(size_t)m * 1280 + n0 + bb];
                xa[4 + r] = xp[(size_t)m * 1280 + n0 + 16 + bb];
            }
        }
        // no end barrier: next step's poll is the synchronization
    }
}

// ---------------------------------------------------------------------------
extern "C" void kernel_launch(void* const* d_in, const int* in_sizes, int n_in,
                              void* d_out, int out_size, void* d_ws, size_t ws_size,
                              hipStream_t stream) {
    const int*   cf    = (const int*)d_in[0];
    const int*   bl    = (const int*)d_in[1];
    const int*   br    = (const int*)d_in[2];
    const int*   scf   = (const int*)d_in[3];
    const int*   sbl   = (const int*)d_in[4];
    const int*   sbr   = (const int*)d_in[5];
    const float* ce    = (const float*)d_in[6];
    const float* be    = (const float*)d_in[7];
    const float* sce   = (const float*)d_in[8];
    const float* sbe   = (const float*)d_in[9];
    const float* Wlin  = (const float*)d_in[10];
    const float* blin  = (const float*)d_in[11];
    const float* Wih_l = (const float*)d_in[12];
    const float* Whh_l = (const float*)d_in[13];
    const float* b_l   = (const float*)d_in[14];
    const float* Wih_r = (const float*)d_in[15];
    const float* Whh_r = (const float*)d_in[16];
    const float* b_r   = (const float*)d_in[17];
    float* out = (float*)d_out;

    // Workspace layout (bytes):
    //   A bf16   [2][32768][320]     :  41,943,040
    //   X bf16   [2][512][64][1280]  : 167,772,160  (ends 209,715,200)
    //   Whh_p bf16 [2][1280][320]    :   1,638,400  (ends 211,353,600)
    //   Wih_p bf16 [2][1280][320]    :   1,638,400  (ends 212,992,000)
    //   bias_p f32 [2][1280]         :      10,240  (ends 213,002,240)
    //   hb_st  i32x4 [2][2][64][100] :     409,600  (ends 213,411,840)
    char* ws = (char*)d_ws;
    __hip_bfloat16* A_b    = (__hip_bfloat16*)(ws);
    __hip_bfloat16* A_l    = A_b;
    __hip_bfloat16* A_r    = A_b + (size_t)32768 * 320;
    __hip_bfloat16* X      = (__hip_bfloat16*)(ws + 41943040);
    __hip_bfloat16* Whh_p  = (__hip_bfloat16*)(ws + 209715200);
    __hip_bfloat16* Wih_p  = (__hip_bfloat16*)(ws + 211353600);
    float*          bias_p = (float*)(ws + 212992000);
    i32x4*          hb_st  = (i32x4*)(ws + 213002240);

    k_prep_w<<<dim3((2 * 1280 * 320 + 255) / 256), dim3(256), 0, stream>>>(
        Whh_l, Whh_r, Wih_l, Wih_r, Whh_p, Wih_p);
    k_prep_misc<<<dim3(1280), dim3(256), 0, stream>>>(b_l, b_r, (int*)hb_st, bias_p);
    k_lin<<<dim3(512, 2), dim3(256), 0, stream>>>(cf, bl, br, scf, sbl, sbr,
                                                  ce, be, sce, sbe, Wlin, blin,
                                                  A_l, A_r);
    k_xgemm<<<dim3(512, 10, 2), dim3(256), 0, stream>>>(A_b, Wih_p, bias_p, X);
    k_rec<<<dim3(80), dim3(256), 0, stream>>>(X, Whh_p, hb_st, out);
}